// Round 1
// baseline (1911.628 us; speedup 1.0000x reference)
//
#include <hip/hip_runtime.h>
#include <hip/hip_bf16.h>

#define N_NODES 50000
#define N_EDGES 800000
#define H 64
#define F 74
#define T 4
#define STEPS 4

// ---------------------------------------------------------------------------
// init: h = h_init = x @ W_in + b_in    [N,74] @ [74,64]
// lane o holds W_in[:,o] in registers; node row via wave-uniform scalar loads.
// block 256 = 4 slots x 64 lanes; each slot processes 16 nodes.
__global__ __launch_bounds__(256) void init_kernel(
    const float* __restrict__ x, const float* __restrict__ W_in,
    const float* __restrict__ b_in, float* __restrict__ h,
    float* __restrict__ h_init, int n_nodes)
{
    const int lane = threadIdx.x & 63;
    const int slot = __builtin_amdgcn_readfirstlane((int)(threadIdx.x >> 6));
    float Wc[F];
#pragma unroll
    for (int i = 0; i < F; ++i) Wc[i] = W_in[i * H + lane];
    const float bias = b_in[lane];
    int n0 = blockIdx.x * 64 + slot * 16;
    for (int k = 0; k < 16; ++k) {
        int n = n0 + k;
        if (n >= n_nodes) break;
        const float* row = x + (size_t)n * F;
        float acc = bias;
#pragma unroll
        for (int i = 0; i < F; ++i) acc = fmaf(row[i], Wc[i], acc);
        h[n * H + lane] = acc;
        h_init[n * H + lane] = acc;
    }
}

// ---------------------------------------------------------------------------
// nt[n,t,o] = sum_i h[n,i] * edge_W[t,i,o]   -> [N, T*H] (256 outputs/node)
// all 256 threads work on the same node; thread = (t,o) pair.
__global__ __launch_bounds__(256) void nt_kernel(
    const float* __restrict__ h, const float* __restrict__ edge_W,
    float* __restrict__ nt, int n_nodes)
{
    const int tid = threadIdx.x;
    const int t = tid >> 6;
    const int o = tid & 63;
    float Wc[H];
#pragma unroll
    for (int i = 0; i < H; ++i) Wc[i] = edge_W[(t * H + i) * H + o];
    int base = blockIdx.x * 64;
    int end = base + 64;
    if (end > n_nodes) end = n_nodes;
    for (int n = base; n < end; ++n) {
        const float* row = h + (size_t)n * H;   // wave-uniform -> s_load
        float acc = 0.f;
#pragma unroll
        for (int i = 0; i < H; ++i) acc = fmaf(row[i], Wc[i], acc);
        nt[(size_t)n * 256 + tid] = acc;
    }
}

// ---------------------------------------------------------------------------
// per-edge: msg = relu(nt[src, etype] + edge_b[etype]); agg[dst] += msg
// one wave per edge (8 edges per wave, 4 waves per block).
__global__ __launch_bounds__(256) void edge_kernel(
    const float* __restrict__ nt, const int* __restrict__ src,
    const int* __restrict__ etype, const int* __restrict__ dst,
    const float* __restrict__ edge_b, float* __restrict__ agg)
{
    const int lane = threadIdx.x & 63;
    const int slot = __builtin_amdgcn_readfirstlane((int)(threadIdx.x >> 6));
    int e0 = (blockIdx.x * 4 + slot) * 8;
#pragma unroll
    for (int k = 0; k < 8; ++k) {
        int e = e0 + k;
        int s = src[e];           // uniform -> s_load
        int t = etype[e];
        int d = dst[e];
        float v = nt[(size_t)s * 256 + t * 64 + lane] + edge_b[t];
        v = fmaxf(v, 0.f);
        atomicAdd(&agg[(size_t)d * H + lane], v);
    }
}

// ---------------------------------------------------------------------------
// GRU: h = GRUCell(agg, h).  6 waves: w<3 -> gi gate w (Wih, agg rows),
// w>=3 -> gh gate w-3 (Whh, h rows). Partials via LDS, combine, in-place h.
#define GRU_NPB 32
__global__ __launch_bounds__(384) void gru_kernel(
    const float* __restrict__ agg, float* __restrict__ h,
    const float* __restrict__ Wih, const float* __restrict__ Whh,
    const float* __restrict__ bih, const float* __restrict__ bhh, int n_nodes)
{
    __shared__ float part[8][6][64];
    const int tid = threadIdx.x;
    const int w = __builtin_amdgcn_readfirstlane(tid >> 6);
    const int lane = tid & 63;
    const int g = (w < 3) ? w : (w - 3);
    const float* Wsel = ((w < 3) ? Wih : Whh) + g * 64 + lane;
    float Wc[H];
#pragma unroll
    for (int i = 0; i < H; ++i) Wc[i] = Wsel[i * 192];
    const float* data = (w < 3) ? agg : h;
    const float bias = (w < 3) ? bih[g * 64 + lane] : bhh[g * 64 + lane];
    const int base = blockIdx.x * GRU_NPB;

    for (int c = 0; c < GRU_NPB; c += 8) {
        for (int j = 0; j < 8; ++j) {
            int n = base + c + j;
            float acc = bias;
            if (n < n_nodes) {
                const float* row = data + (size_t)n * H;  // uniform -> s_load
#pragma unroll
                for (int i = 0; i < H; ++i) acc = fmaf(row[i], Wc[i], acc);
            }
            part[j][w][lane] = acc;
        }
        __syncthreads();
        for (int idx = tid; idx < 512; idx += 384) {
            int j = idx >> 6, o = idx & 63;
            int n = base + c + j;
            if (n < n_nodes) {
                float ir = part[j][0][o], iz = part[j][1][o], in_ = part[j][2][o];
                float hr = part[j][3][o], hz = part[j][4][o], hn = part[j][5][o];
                float r = 1.f / (1.f + expf(-(ir + hr)));
                float z = 1.f / (1.f + expf(-(iz + hz)));
                float nn = tanhf(in_ + r * hn);
                float hv = h[(size_t)n * H + o];
                h[(size_t)n * H + o] = (1.f - z) * nn + z * hv;
            }
        }
        __syncthreads();
    }
}

// ---------------------------------------------------------------------------
// MLP stage 1: hidden = relu([h_init, h] @ W1 + b1)   W1: [128][64]
__global__ __launch_bounds__(256) void mlp1_kernel(
    const float* __restrict__ h_init, const float* __restrict__ h,
    const float* __restrict__ W1, const float* __restrict__ b1,
    float* __restrict__ hidden, int n_nodes)
{
    const int lane = threadIdx.x & 63;
    const int slot = __builtin_amdgcn_readfirstlane((int)(threadIdx.x >> 6));
    float Wa[H], Wb[H];
#pragma unroll
    for (int i = 0; i < H; ++i) Wa[i] = W1[i * H + lane];
#pragma unroll
    for (int i = 0; i < H; ++i) Wb[i] = W1[(H + i) * H + lane];
    const float bias = b1[lane];
    int n0 = blockIdx.x * 64 + slot * 16;
    for (int k = 0; k < 16; ++k) {
        int n = n0 + k;
        if (n >= n_nodes) break;
        const float* ra = h_init + (size_t)n * H;
        const float* rb = h + (size_t)n * H;
        float acc = bias;
#pragma unroll
        for (int i = 0; i < H; ++i) acc = fmaf(ra[i], Wa[i], acc);
#pragma unroll
        for (int i = 0; i < H; ++i) acc = fmaf(rb[i], Wb[i], acc);
        hidden[n * H + lane] = fmaxf(acc, 0.f);
    }
}

// MLP stage 2: out = tanh(hidden @ W2 + b2)   W2: [64][64]
__global__ __launch_bounds__(256) void mlp2_kernel(
    const float* __restrict__ hidden, const float* __restrict__ W2,
    const float* __restrict__ b2, float* __restrict__ out, int n_nodes)
{
    const int lane = threadIdx.x & 63;
    const int slot = __builtin_amdgcn_readfirstlane((int)(threadIdx.x >> 6));
    float Wc[H];
#pragma unroll
    for (int i = 0; i < H; ++i) Wc[i] = W2[i * H + lane];
    const float bias = b2[lane];
    int n0 = blockIdx.x * 64 + slot * 16;
    for (int k = 0; k < 16; ++k) {
        int n = n0 + k;
        if (n >= n_nodes) break;
        const float* row = hidden + (size_t)n * H;
        float acc = bias;
#pragma unroll
        for (int i = 0; i < H; ++i) acc = fmaf(row[i], Wc[i], acc);
        out[n * H + lane] = tanhf(acc);
    }
}

// ---------------------------------------------------------------------------
extern "C" void kernel_launch(void* const* d_in, const int* in_sizes, int n_in,
                              void* d_out, int out_size, void* d_ws, size_t ws_size,
                              hipStream_t stream)
{
    const float* x      = (const float*)d_in[0];
    const int*   etype  = (const int*)  d_in[1];
    const int*   src    = (const int*)  d_in[2];
    const int*   dst    = (const int*)  d_in[3];
    const float* W_in   = (const float*)d_in[4];
    const float* b_in   = (const float*)d_in[5];
    const float* edge_W = (const float*)d_in[6];
    const float* edge_b = (const float*)d_in[7];
    const float* gWih   = (const float*)d_in[8];
    const float* gWhh   = (const float*)d_in[9];
    const float* gbih   = (const float*)d_in[10];
    const float* gbhh   = (const float*)d_in[11];
    const float* W1     = (const float*)d_in[12];
    const float* b1     = (const float*)d_in[13];
    const float* W2     = (const float*)d_in[14];
    const float* b2     = (const float*)d_in[15];
    float* out = (float*)d_out;

    const size_t NH_BYTES = (size_t)N_NODES * H * sizeof(float);   // 12.8 MB
    char* ws = (char*)d_ws;
    float* h      = (float*)(ws);
    float* h_init = (float*)(ws + NH_BYTES);
    float* nt     = (float*)(ws + 2 * NH_BYTES);                    // N*T*H = 51.2 MB
    float* agg    = (float*)(ws + 2 * NH_BYTES + (size_t)N_NODES * T * H * sizeof(float));
    float* hidden = agg;  // reuse (agg dead after last GRU)

    const int node_blocks = (N_NODES + 63) / 64;     // 782
    const int gru_blocks  = (N_NODES + GRU_NPB - 1) / GRU_NPB; // 1563
    const int edge_blocks = N_EDGES / 32;            // 25000

    init_kernel<<<node_blocks, 256, 0, stream>>>(x, W_in, b_in, h, h_init, N_NODES);

    for (int s = 0; s < STEPS; ++s) {
        nt_kernel<<<node_blocks, 256, 0, stream>>>(h, edge_W, nt, N_NODES);
        hipMemsetAsync(agg, 0, NH_BYTES, stream);
        edge_kernel<<<edge_blocks, 256, 0, stream>>>(nt, src, etype, dst, edge_b, agg);
        gru_kernel<<<gru_blocks, 384, 0, stream>>>(agg, h, gWih, gWhh, gbih, gbhh, N_NODES);
    }

    mlp1_kernel<<<node_blocks, 256, 0, stream>>>(h_init, h, W1, b1, hidden, N_NODES);
    mlp2_kernel<<<node_blocks, 256, 0, stream>>>(hidden, W2, b2, out, N_NODES);
}

// Round 2
// 1910.898 us; speedup vs baseline: 1.0004x; 1.0004x over previous
//
#include <hip/hip_runtime.h>
#include <hip/hip_bf16.h>

#define N_NODES 50000
#define N_EDGES 800000
#define H 64
#define F 74
#define T 4
#define STEPS 4

// ---------------------------------------------------------------------------
// init: h = h_init = x @ W_in + b_in    [N,74] @ [74,64]
// lane o holds W_in[:,o] in 74 VGPRs (launch_bounds cap 128 so it stays
// register-resident); 8-node ILP per group.
__global__ __launch_bounds__(256, 4) void init_kernel(
    const float* __restrict__ x, const float* __restrict__ W_in,
    const float* __restrict__ b_in, float* __restrict__ h,
    float* __restrict__ h_init, int n_nodes)
{
    const int lane = threadIdx.x & 63;
    const int slot = __builtin_amdgcn_readfirstlane((int)(threadIdx.x >> 6));
    float Wc[F];
#pragma unroll
    for (int i = 0; i < F; ++i) Wc[i] = W_in[i * H + lane];
    const float bias = b_in[lane];
    const int n0 = blockIdx.x * 64 + slot * 16;
    for (int c = 0; c < 16; c += 8) {
        float acc[8];
#pragma unroll
        for (int j = 0; j < 8; ++j) acc[j] = bias;
#pragma unroll
        for (int j = 0; j < 8; ++j) {
            int n = n0 + c + j;
            if (n < n_nodes) {
                const float* row = x + (size_t)n * F;   // wave-uniform
#pragma unroll
                for (int i = 0; i < F; ++i) acc[j] = fmaf(row[i], Wc[i], acc[j]);
            }
        }
#pragma unroll
        for (int j = 0; j < 8; ++j) {
            int n = n0 + c + j;
            if (n < n_nodes) {
                h[(size_t)n * H + lane] = acc[j];
                h_init[(size_t)n * H + lane] = acc[j];
            }
        }
    }
}

// ---------------------------------------------------------------------------
// ntr[n,t,o] = relu( sum_i h[n,i] * edge_W[t,i,o] + edge_b[t] )
// bias+ReLU fused here (they depend only on (n,t,o), not the edge).
// thread = (t,o); weights register-resident; 8-node ILP.
__global__ __launch_bounds__(256, 4) void nt_kernel(
    const float* __restrict__ h, const float* __restrict__ edge_W,
    const float* __restrict__ edge_b, float* __restrict__ ntr, int n_nodes)
{
    const int tid = threadIdx.x;
    const int t = __builtin_amdgcn_readfirstlane(tid >> 6);
    const int o = tid & 63;
    float Wc[H];
#pragma unroll
    for (int i = 0; i < H; ++i) Wc[i] = edge_W[(t * H + i) * H + o];
    const float bias = edge_b[t];
    const int base = blockIdx.x * 64;
    for (int c = 0; c < 64; c += 8) {
        float acc[8];
#pragma unroll
        for (int j = 0; j < 8; ++j) acc[j] = bias;
#pragma unroll
        for (int j = 0; j < 8; ++j) {
            int n = base + c + j;
            if (n < n_nodes) {
                const float* row = h + (size_t)n * H;   // wave-uniform
#pragma unroll
                for (int i = 0; i < H; ++i) acc[j] = fmaf(row[i], Wc[i], acc[j]);
            }
        }
#pragma unroll
        for (int j = 0; j < 8; ++j) {
            int n = base + c + j;
            if (n < n_nodes)
                ntr[(size_t)n * 256 + t * 64 + o] = fmaxf(acc[j], 0.f);
        }
    }
}

// ---------------------------------------------------------------------------
// per-edge: agg[dst] += ntr[src, etype]   (pure gather + atomic scatter)
__global__ __launch_bounds__(256) void edge_kernel(
    const float* __restrict__ ntr, const int* __restrict__ src,
    const int* __restrict__ etype, const int* __restrict__ dst,
    float* __restrict__ agg)
{
    const int lane = threadIdx.x & 63;
    const int slot = __builtin_amdgcn_readfirstlane((int)(threadIdx.x >> 6));
    int e0 = (blockIdx.x * 4 + slot) * 8;
#pragma unroll
    for (int k = 0; k < 8; ++k) {
        int e = e0 + k;
        int s = src[e];           // uniform -> s_load
        int t = etype[e];
        int d = dst[e];
        float v = ntr[(size_t)s * 256 + t * 64 + lane];
        atomicAdd(&agg[(size_t)d * H + lane], v);
    }
}

// ---------------------------------------------------------------------------
// GRU: h = GRUCell(agg, h). 6 waves: w<3 -> gi gate w (Wih, agg rows),
// w>=3 -> gh gate w-3 (Whh, h rows). Register-resident weights, 8-node ILP,
// partials via LDS, combine in-place.
#define GRU_NPB 64
__global__ __launch_bounds__(384, 4) void gru_kernel(
    const float* __restrict__ agg, float* __restrict__ h,
    const float* __restrict__ Wih, const float* __restrict__ Whh,
    const float* __restrict__ bih, const float* __restrict__ bhh, int n_nodes)
{
    __shared__ float part[8][6][64];
    const int tid = threadIdx.x;
    const int w = __builtin_amdgcn_readfirstlane(tid >> 6);
    const int lane = tid & 63;
    const int g = (w < 3) ? w : (w - 3);
    const float* Wsel = ((w < 3) ? Wih : Whh) + g * 64 + lane;
    float Wc[H];
#pragma unroll
    for (int i = 0; i < H; ++i) Wc[i] = Wsel[i * 192];
    const float* data = (w < 3) ? agg : h;
    const float bias = (w < 3) ? bih[g * 64 + lane] : bhh[g * 64 + lane];
    const int base = blockIdx.x * GRU_NPB;

    for (int c = 0; c < GRU_NPB; c += 8) {
        float acc[8];
#pragma unroll
        for (int j = 0; j < 8; ++j) acc[j] = bias;
#pragma unroll
        for (int j = 0; j < 8; ++j) {
            int n = base + c + j;
            if (n < n_nodes) {
                const float* row = data + (size_t)n * H;  // wave-uniform
#pragma unroll
                for (int i = 0; i < H; ++i) acc[j] = fmaf(row[i], Wc[i], acc[j]);
            }
        }
#pragma unroll
        for (int j = 0; j < 8; ++j) part[j][w][lane] = acc[j];
        __syncthreads();
        for (int idx = tid; idx < 512; idx += 384) {
            int j = idx >> 6, o = idx & 63;
            int n = base + c + j;
            if (n < n_nodes) {
                float ir = part[j][0][o], iz = part[j][1][o], in_ = part[j][2][o];
                float hr = part[j][3][o], hz = part[j][4][o], hn = part[j][5][o];
                float r = 1.f / (1.f + expf(-(ir + hr)));
                float z = 1.f / (1.f + expf(-(iz + hz)));
                float nn = tanhf(in_ + r * hn);
                float hv = h[(size_t)n * H + o];
                h[(size_t)n * H + o] = (1.f - z) * nn + z * hv;
            }
        }
        __syncthreads();
    }
}

// ---------------------------------------------------------------------------
// MLP stage 1: hidden = relu([h_init, h] @ W1 + b1)   W1: [128][64]
// 128 weight regs -> cap 256 (launch_bounds min 2 waves/EU).
__global__ __launch_bounds__(256, 2) void mlp1_kernel(
    const float* __restrict__ h_init, const float* __restrict__ h,
    const float* __restrict__ W1, const float* __restrict__ b1,
    float* __restrict__ hidden, int n_nodes)
{
    const int lane = threadIdx.x & 63;
    const int slot = __builtin_amdgcn_readfirstlane((int)(threadIdx.x >> 6));
    float Wa[H], Wb[H];
#pragma unroll
    for (int i = 0; i < H; ++i) Wa[i] = W1[i * H + lane];
#pragma unroll
    for (int i = 0; i < H; ++i) Wb[i] = W1[(H + i) * H + lane];
    const float bias = b1[lane];
    const int n0 = blockIdx.x * 64 + slot * 16;
    for (int c = 0; c < 16; c += 8) {
        float acc[8];
#pragma unroll
        for (int j = 0; j < 8; ++j) acc[j] = bias;
#pragma unroll
        for (int j = 0; j < 8; ++j) {
            int n = n0 + c + j;
            if (n < n_nodes) {
                const float* ra = h_init + (size_t)n * H;
                const float* rb = h + (size_t)n * H;
#pragma unroll
                for (int i = 0; i < H; ++i) acc[j] = fmaf(ra[i], Wa[i], acc[j]);
#pragma unroll
                for (int i = 0; i < H; ++i) acc[j] = fmaf(rb[i], Wb[i], acc[j]);
            }
        }
#pragma unroll
        for (int j = 0; j < 8; ++j) {
            int n = n0 + c + j;
            if (n < n_nodes) hidden[(size_t)n * H + lane] = fmaxf(acc[j], 0.f);
        }
    }
}

// MLP stage 2: out = tanh(hidden @ W2 + b2)
__global__ __launch_bounds__(256, 4) void mlp2_kernel(
    const float* __restrict__ hidden, const float* __restrict__ W2,
    const float* __restrict__ b2, float* __restrict__ out, int n_nodes)
{
    const int lane = threadIdx.x & 63;
    const int slot = __builtin_amdgcn_readfirstlane((int)(threadIdx.x >> 6));
    float Wc[H];
#pragma unroll
    for (int i = 0; i < H; ++i) Wc[i] = W2[i * H + lane];
    const float bias = b2[lane];
    const int n0 = blockIdx.x * 64 + slot * 16;
    for (int c = 0; c < 16; c += 8) {
        float acc[8];
#pragma unroll
        for (int j = 0; j < 8; ++j) acc[j] = bias;
#pragma unroll
        for (int j = 0; j < 8; ++j) {
            int n = n0 + c + j;
            if (n < n_nodes) {
                const float* row = hidden + (size_t)n * H;
#pragma unroll
                for (int i = 0; i < H; ++i) acc[j] = fmaf(row[i], Wc[i], acc[j]);
            }
        }
#pragma unroll
        for (int j = 0; j < 8; ++j) {
            int n = n0 + c + j;
            if (n < n_nodes) out[(size_t)n * H + lane] = tanhf(acc[j]);
        }
    }
}

// ---------------------------------------------------------------------------
extern "C" void kernel_launch(void* const* d_in, const int* in_sizes, int n_in,
                              void* d_out, int out_size, void* d_ws, size_t ws_size,
                              hipStream_t stream)
{
    const float* x      = (const float*)d_in[0];
    const int*   etype  = (const int*)  d_in[1];
    const int*   src    = (const int*)  d_in[2];
    const int*   dst    = (const int*)  d_in[3];
    const float* W_in   = (const float*)d_in[4];
    const float* b_in   = (const float*)d_in[5];
    const float* edge_W = (const float*)d_in[6];
    const float* edge_b = (const float*)d_in[7];
    const float* gWih   = (const float*)d_in[8];
    const float* gWhh   = (const float*)d_in[9];
    const float* gbih   = (const float*)d_in[10];
    const float* gbhh   = (const float*)d_in[11];
    const float* W1     = (const float*)d_in[12];
    const float* b1     = (const float*)d_in[13];
    const float* W2     = (const float*)d_in[14];
    const float* b2     = (const float*)d_in[15];
    float* out = (float*)d_out;

    const size_t NH_BYTES = (size_t)N_NODES * H * sizeof(float);   // 12.8 MB
    char* ws = (char*)d_ws;
    float* h      = (float*)(ws);
    float* h_init = (float*)(ws + NH_BYTES);
    float* ntr    = (float*)(ws + 2 * NH_BYTES);                    // 51.2 MB
    float* agg    = (float*)(ws + 2 * NH_BYTES + (size_t)N_NODES * T * H * sizeof(float));
    float* hidden = agg;  // reuse (agg dead after last GRU)

    const int node_blocks = (N_NODES + 63) / 64;     // 782
    const int gru_blocks  = (N_NODES + GRU_NPB - 1) / GRU_NPB; // 782
    const int edge_blocks = N_EDGES / 32;            // 25000

    init_kernel<<<node_blocks, 256, 0, stream>>>(x, W_in, b_in, h, h_init, N_NODES);

    for (int s = 0; s < STEPS; ++s) {
        nt_kernel<<<node_blocks, 256, 0, stream>>>(h, edge_W, edge_b, ntr, N_NODES);
        hipMemsetAsync(agg, 0, NH_BYTES, stream);
        edge_kernel<<<edge_blocks, 256, 0, stream>>>(ntr, src, etype, dst, agg);
        gru_kernel<<<gru_blocks, 384, 0, stream>>>(agg, h, gWih, gWhh, gbih, gbhh, N_NODES);
    }

    mlp1_kernel<<<node_blocks, 256, 0, stream>>>(h_init, h, W1, b1, hidden, N_NODES);
    mlp2_kernel<<<node_blocks, 256, 0, stream>>>(hidden, W2, b2, out, N_NODES);
}

// Round 3
// 990.857 us; speedup vs baseline: 1.9293x; 1.9285x over previous
//
#include <hip/hip_runtime.h>
#include <hip/hip_bf16.h>

#define N_NODES 50000
#define N_EDGES 800000
#define H 64
#define F 74
#define T 4
#define STEPS 4

// Keep a value register-resident: opaque producer, cannot be rematerialized.
#define KEEP(x) asm volatile("" : "+v"(x))

// ---------------------------------------------------------------------------
// init: h = h_init = x @ W_in + b_in    [N,74] @ [74,64]
__global__ __launch_bounds__(256, 4) void init_kernel(
    const float* __restrict__ x, const float* __restrict__ W_in,
    const float* __restrict__ b_in, float* __restrict__ h,
    float* __restrict__ h_init, int n_nodes)
{
    const int lane = threadIdx.x & 63;
    const int slot = __builtin_amdgcn_readfirstlane((int)(threadIdx.x >> 6));
    float Wc[F];
#pragma unroll
    for (int i = 0; i < F; ++i) Wc[i] = W_in[i * H + lane];
#pragma unroll
    for (int i = 0; i < F; ++i) KEEP(Wc[i]);
    const float bias = b_in[lane];
    const int n0 = blockIdx.x * 64 + slot * 16;
    for (int c = 0; c < 16; c += 8) {
        float acc[8];
#pragma unroll
        for (int j = 0; j < 8; ++j) acc[j] = bias;
#pragma unroll
        for (int j = 0; j < 8; ++j) {
            int n = n0 + c + j;
            if (n < n_nodes) {
                const float* row = x + (size_t)n * F;   // wave-uniform -> s_load
#pragma unroll
                for (int i = 0; i < F; ++i) acc[j] = fmaf(row[i], Wc[i], acc[j]);
            }
        }
#pragma unroll
        for (int j = 0; j < 8; ++j) {
            int n = n0 + c + j;
            if (n < n_nodes) {
                h[(size_t)n * H + lane] = acc[j];
                h_init[(size_t)n * H + lane] = acc[j];
            }
        }
    }
}

// ---------------------------------------------------------------------------
// ntr[n, t*64+o] = relu( sum_i h[n,i] * edge_W[t,i,o] + edge_b[t] )
__global__ __launch_bounds__(256, 4) void nt_kernel(
    const float* __restrict__ h, const float* __restrict__ edge_W,
    const float* __restrict__ edge_b, float* __restrict__ ntr, int n_nodes)
{
    const int tid = threadIdx.x;
    const int t = __builtin_amdgcn_readfirstlane(tid >> 6);
    const int o = tid & 63;
    float Wc[H];
#pragma unroll
    for (int i = 0; i < H; ++i) Wc[i] = edge_W[(t * H + i) * H + o];
#pragma unroll
    for (int i = 0; i < H; ++i) KEEP(Wc[i]);
    const float bias = edge_b[t];
    const int base = blockIdx.x * 64;
    for (int c = 0; c < 64; c += 8) {
        float acc[8];
#pragma unroll
        for (int j = 0; j < 8; ++j) acc[j] = bias;
#pragma unroll
        for (int j = 0; j < 8; ++j) {
            int n = base + c + j;
            if (n < n_nodes) {
                const float* row = h + (size_t)n * H;   // read-only -> s_load
#pragma unroll
                for (int i = 0; i < H; ++i) acc[j] = fmaf(row[i], Wc[i], acc[j]);
            }
        }
#pragma unroll
        for (int j = 0; j < 8; ++j) {
            int n = base + c + j;
            if (n < n_nodes)
                ntr[(size_t)n * 256 + t * 64 + o] = fmaxf(acc[j], 0.f);
        }
    }
}

// ---------------------------------------------------------------------------
// CSR build: degree count, exclusive scan, fill (packed rec = src*4 + etype)
__global__ __launch_bounds__(256) void deg_kernel(
    const int* __restrict__ dst, int* __restrict__ deg)
{
    int e = blockIdx.x * 256 + threadIdx.x;
    if (e < N_EDGES) atomicAdd(&deg[dst[e]], 1);
}

__global__ __launch_bounds__(1024) void scan_kernel(
    const int* __restrict__ deg, int* __restrict__ row_ptr,
    int* __restrict__ cursor)
{
    __shared__ int wsum[16];
    __shared__ int wpre[16];
    __shared__ int btot;
    const int tid = threadIdx.x;
    const int lane = tid & 63;
    const int w = tid >> 6;
    int running = 0;
    for (int base = 0; base < N_NODES; base += 1024) {
        int idx = base + tid;
        int v = (idx < N_NODES) ? deg[idx] : 0;
        int x = v;
#pragma unroll
        for (int off = 1; off < 64; off <<= 1) {
            int u = __shfl_up(x, off, 64);
            if (lane >= off) x += u;
        }
        if (lane == 63) wsum[w] = x;
        __syncthreads();
        if (w == 0) {
            int s = (lane < 16) ? wsum[lane & 15] : 0;
#pragma unroll
            for (int off = 1; off < 16; off <<= 1) {
                int u = __shfl_up(s, off, 64);
                if (lane >= off) s += u;
            }
            if (lane < 16) wpre[lane] = s - wsum[lane];
            if (lane == 15) btot = s;
        }
        __syncthreads();
        int excl = running + wpre[w] + (x - v);
        if (idx < N_NODES) { row_ptr[idx] = excl; cursor[idx] = excl; }
        running += btot;
        __syncthreads();
    }
    if (tid == 0) row_ptr[N_NODES] = running;
}

__global__ __launch_bounds__(256) void fill_kernel(
    const int* __restrict__ src, const int* __restrict__ etype,
    const int* __restrict__ dst, int* __restrict__ cursor,
    int* __restrict__ ss)
{
    int e = blockIdx.x * 256 + threadIdx.x;
    if (e < N_EDGES) {
        int p = atomicAdd(&cursor[dst[e]], 1);
        ss[p] = src[e] * 4 + etype[e];
    }
}

// ---------------------------------------------------------------------------
// agg[d] = sum over incoming edges of ntr[rec]  (no atomics; wave per node)
__global__ __launch_bounds__(256) void agg_kernel(
    const float* __restrict__ ntr, const int* __restrict__ row_ptr,
    const int* __restrict__ ss, float* __restrict__ agg)
{
    const int lane = threadIdx.x & 63;
    const int w = __builtin_amdgcn_readfirstlane((int)(threadIdx.x >> 6));
    const int d = blockIdx.x * 4 + w;
    if (d >= N_NODES) return;
    const int beg = row_ptr[d];
    const int end = row_ptr[d + 1];
    float acc = 0.f;
    int p = beg;
    for (; p + 8 <= end; p += 8) {
        int r0 = ss[p + 0], r1 = ss[p + 1], r2 = ss[p + 2], r3 = ss[p + 3];
        int r4 = ss[p + 4], r5 = ss[p + 5], r6 = ss[p + 6], r7 = ss[p + 7];
        float v0 = ntr[(size_t)r0 * 64 + lane];
        float v1 = ntr[(size_t)r1 * 64 + lane];
        float v2 = ntr[(size_t)r2 * 64 + lane];
        float v3 = ntr[(size_t)r3 * 64 + lane];
        float v4 = ntr[(size_t)r4 * 64 + lane];
        float v5 = ntr[(size_t)r5 * 64 + lane];
        float v6 = ntr[(size_t)r6 * 64 + lane];
        float v7 = ntr[(size_t)r7 * 64 + lane];
        acc += ((v0 + v1) + (v2 + v3)) + ((v4 + v5) + (v6 + v7));
    }
    for (; p < end; ++p) {
        int r = ss[p];
        acc += ntr[(size_t)r * 64 + lane];
    }
    agg[(size_t)d * H + lane] = acc;
}

// ---------------------------------------------------------------------------
// GRU: h_out = GRUCell(agg, h_in). h_in is read-only (ping-pong) so row
// loads scalarize; weights pinned with KEEP.
#define GRU_NPB 64
__global__ __launch_bounds__(384, 4) void gru_kernel(
    const float* __restrict__ agg, const float* __restrict__ h_in,
    float* __restrict__ h_out,
    const float* __restrict__ Wih, const float* __restrict__ Whh,
    const float* __restrict__ bih, const float* __restrict__ bhh, int n_nodes)
{
    __shared__ float part[8][6][64];
    const int tid = threadIdx.x;
    const int w = __builtin_amdgcn_readfirstlane(tid >> 6);
    const int lane = tid & 63;
    const int g = (w < 3) ? w : (w - 3);
    const float* Wsel = ((w < 3) ? Wih : Whh) + g * 64 + lane;
    float Wc[H];
#pragma unroll
    for (int i = 0; i < H; ++i) Wc[i] = Wsel[i * 192];
#pragma unroll
    for (int i = 0; i < H; ++i) KEEP(Wc[i]);
    const float* data = (w < 3) ? agg : h_in;
    const float bias = (w < 3) ? bih[g * 64 + lane] : bhh[g * 64 + lane];
    const int base = blockIdx.x * GRU_NPB;

    for (int c = 0; c < GRU_NPB; c += 8) {
        float acc[8];
#pragma unroll
        for (int j = 0; j < 8; ++j) acc[j] = bias;
#pragma unroll
        for (int j = 0; j < 8; ++j) {
            int n = base + c + j;
            if (n < n_nodes) {
                const float* row = data + (size_t)n * H;  // read-only -> s_load
#pragma unroll
                for (int i = 0; i < H; ++i) acc[j] = fmaf(row[i], Wc[i], acc[j]);
            }
        }
#pragma unroll
        for (int j = 0; j < 8; ++j) part[j][w][lane] = acc[j];
        __syncthreads();
        for (int idx = tid; idx < 512; idx += 384) {
            int j = idx >> 6, o = idx & 63;
            int n = base + c + j;
            if (n < n_nodes) {
                float ir = part[j][0][o], iz = part[j][1][o], in_ = part[j][2][o];
                float hr = part[j][3][o], hz = part[j][4][o], hn = part[j][5][o];
                float r = 1.f / (1.f + __expf(-(ir + hr)));
                float z = 1.f / (1.f + __expf(-(iz + hz)));
                float e2 = __expf(2.f * (in_ + r * hn));
                float nn = 1.f - 2.f / (e2 + 1.f);     // tanh
                float hv = h_in[(size_t)n * H + o];
                h_out[(size_t)n * H + o] = (1.f - z) * nn + z * hv;
            }
        }
        __syncthreads();
    }
}

// ---------------------------------------------------------------------------
// MLP stage 1: hidden = relu([h_init, h] @ W1 + b1)   W1: [128][64]
__global__ __launch_bounds__(256, 2) void mlp1_kernel(
    const float* __restrict__ h_init, const float* __restrict__ h,
    const float* __restrict__ W1, const float* __restrict__ b1,
    float* __restrict__ hidden, int n_nodes)
{
    const int lane = threadIdx.x & 63;
    const int slot = __builtin_amdgcn_readfirstlane((int)(threadIdx.x >> 6));
    float Wa[H], Wb[H];
#pragma unroll
    for (int i = 0; i < H; ++i) Wa[i] = W1[i * H + lane];
#pragma unroll
    for (int i = 0; i < H; ++i) Wb[i] = W1[(H + i) * H + lane];
#pragma unroll
    for (int i = 0; i < H; ++i) { KEEP(Wa[i]); KEEP(Wb[i]); }
    const float bias = b1[lane];
    const int n0 = blockIdx.x * 64 + slot * 16;
    for (int c = 0; c < 16; c += 8) {
        float acc[8];
#pragma unroll
        for (int j = 0; j < 8; ++j) acc[j] = bias;
#pragma unroll
        for (int j = 0; j < 8; ++j) {
            int n = n0 + c + j;
            if (n < n_nodes) {
                const float* ra = h_init + (size_t)n * H;
                const float* rb = h + (size_t)n * H;
#pragma unroll
                for (int i = 0; i < H; ++i) acc[j] = fmaf(ra[i], Wa[i], acc[j]);
#pragma unroll
                for (int i = 0; i < H; ++i) acc[j] = fmaf(rb[i], Wb[i], acc[j]);
            }
        }
#pragma unroll
        for (int j = 0; j < 8; ++j) {
            int n = n0 + c + j;
            if (n < n_nodes) hidden[(size_t)n * H + lane] = fmaxf(acc[j], 0.f);
        }
    }
}

// MLP stage 2: out = tanh(hidden @ W2 + b2)
__global__ __launch_bounds__(256, 4) void mlp2_kernel(
    const float* __restrict__ hidden, const float* __restrict__ W2,
    const float* __restrict__ b2, float* __restrict__ out, int n_nodes)
{
    const int lane = threadIdx.x & 63;
    const int slot = __builtin_amdgcn_readfirstlane((int)(threadIdx.x >> 6));
    float Wc[H];
#pragma unroll
    for (int i = 0; i < H; ++i) Wc[i] = W2[i * H + lane];
#pragma unroll
    for (int i = 0; i < H; ++i) KEEP(Wc[i]);
    const float bias = b2[lane];
    const int n0 = blockIdx.x * 64 + slot * 16;
    for (int c = 0; c < 16; c += 8) {
        float acc[8];
#pragma unroll
        for (int j = 0; j < 8; ++j) acc[j] = bias;
#pragma unroll
        for (int j = 0; j < 8; ++j) {
            int n = n0 + c + j;
            if (n < n_nodes) {
                const float* row = hidden + (size_t)n * H;
#pragma unroll
                for (int i = 0; i < H; ++i) acc[j] = fmaf(row[i], Wc[i], acc[j]);
            }
        }
#pragma unroll
        for (int j = 0; j < 8; ++j) {
            int n = n0 + c + j;
            if (n < n_nodes) {
                float x = acc[j];
                float e2 = __expf(2.f * x);
                out[(size_t)n * H + lane] = 1.f - 2.f / (e2 + 1.f);
            }
        }
    }
}

// ---------------------------------------------------------------------------
extern "C" void kernel_launch(void* const* d_in, const int* in_sizes, int n_in,
                              void* d_out, int out_size, void* d_ws, size_t ws_size,
                              hipStream_t stream)
{
    const float* x      = (const float*)d_in[0];
    const int*   etype  = (const int*)  d_in[1];
    const int*   src    = (const int*)  d_in[2];
    const int*   dst    = (const int*)  d_in[3];
    const float* W_in   = (const float*)d_in[4];
    const float* b_in   = (const float*)d_in[5];
    const float* edge_W = (const float*)d_in[6];
    const float* edge_b = (const float*)d_in[7];
    const float* gWih   = (const float*)d_in[8];
    const float* gWhh   = (const float*)d_in[9];
    const float* gbih   = (const float*)d_in[10];
    const float* gbhh   = (const float*)d_in[11];
    const float* W1     = (const float*)d_in[12];
    const float* b1     = (const float*)d_in[13];
    const float* W2     = (const float*)d_in[14];
    const float* b2     = (const float*)d_in[15];
    float* out = (float*)d_out;

    const size_t NH = (size_t)N_NODES * H;                 // 3.2M floats
    const size_t NTR = (size_t)N_NODES * 256;              // 12.8M floats
    char* ws = (char*)d_ws;
    float* hA     = (float*)(ws);
    float* hB     = (float*)(ws + NH * 4);
    float* h_init = (float*)(ws + 2 * NH * 4);
    float* ntr    = (float*)(ws + 3 * NH * 4);
    float* agg    = (float*)(ws + 3 * NH * 4 + NTR * 4);
    int*   deg    = (int*)  (ws + 4 * NH * 4 + NTR * 4);
    int*   rowp   = (int*)  (deg + N_NODES);
    int*   cursor = (int*)  (rowp + N_NODES + 1);
    int*   ss     = (int*)  (cursor + N_NODES);
    float* hidden = agg;  // reuse

    const int node_blocks = (N_NODES + 63) / 64;      // 782
    const int edge_tblocks = (N_EDGES + 255) / 256;   // 3125
    const int agg_blocks = (N_NODES + 3) / 4;         // 12500

    // CSR build (once per call)
    hipMemsetAsync(deg, 0, N_NODES * sizeof(int), stream);
    deg_kernel<<<edge_tblocks, 256, 0, stream>>>(dst, deg);
    scan_kernel<<<1, 1024, 0, stream>>>(deg, rowp, cursor);
    fill_kernel<<<edge_tblocks, 256, 0, stream>>>(src, etype, dst, cursor, ss);

    init_kernel<<<node_blocks, 256, 0, stream>>>(x, W_in, b_in, hA, h_init, N_NODES);

    float* hcur = hA;
    float* hnxt = hB;
    for (int s = 0; s < STEPS; ++s) {
        nt_kernel<<<node_blocks, 256, 0, stream>>>(hcur, edge_W, edge_b, ntr, N_NODES);
        agg_kernel<<<agg_blocks, 256, 0, stream>>>(ntr, rowp, ss, agg);
        gru_kernel<<<node_blocks, 384, 0, stream>>>(agg, hcur, hnxt,
                                                    gWih, gWhh, gbih, gbhh, N_NODES);
        float* tmp = hcur; hcur = hnxt; hnxt = tmp;
    }
    // after 4 steps, hcur == hA

    mlp1_kernel<<<node_blocks, 256, 0, stream>>>(h_init, hcur, W1, b1, hidden, N_NODES);
    mlp2_kernel<<<node_blocks, 256, 0, stream>>>(hidden, W2, b2, out, N_NODES);
}

// Round 4
// 597.664 us; speedup vs baseline: 3.1985x; 1.6579x over previous
//
#include <hip/hip_runtime.h>
#include <hip/hip_bf16.h>

#define N_NODES 50000
#define M2      50048          // padded to multiple of 64
#define N_EDGES 800000
#define H 64
#define F 74
#define T 4
#define STEPS 4
#define NTILES16 (M2/16)       // 3128 wave-tiles of 16 rows

using short8 = __attribute__((ext_vector_type(8))) short;
using f32x4  = __attribute__((ext_vector_type(4))) float;
typedef unsigned short ushort_t;

#define MFMA(a,b,c) __builtin_amdgcn_mfma_f32_16x16x32_bf16(a,b,c,0,0,0)

static __device__ inline float b2f(ushort_t u) {
    union { unsigned int i; float f; } c; c.i = ((unsigned int)u) << 16; return c.f;
}
static __device__ inline ushort_t f2b(float v) {
    union { __hip_bfloat16 b; ushort_t u; } c; c.b = __float2bfloat16(v); return c.u;
}
static __device__ inline void split_store(ushort_t* hi, ushort_t* lo, size_t ix, float v) {
    ushort_t h = f2b(v);
    hi[ix] = h;
    lo[ix] = f2b(v - b2f(h));
}
static __device__ inline float sigm(float x) { return 1.f / (1.f + __expf(-x)); }
static __device__ inline float tanh_f(float x) {
    float e2 = __expf(2.f * x); return 1.f - 2.f / (e2 + 1.f);
}

// ---- LDS staging of B-tiles (bf16, row-major [rows][KW8*8]) with XOR swizzle
template<int KW8>
static __device__ inline void stage_tile(const ushort_t* __restrict__ g, ushort_t* l,
                                         int rows, int tid) {
    const int chunks = rows * KW8;
    for (int i = tid; i < chunks; i += 256) {
        int row = i / KW8, kg = i - row * KW8;
        short8 v = *(const short8*)(g + (size_t)row * (KW8 * 8) + kg * 8);
        int b = (row * (KW8 * 16) + kg * 16) ^ ((row & 7) << 4);
        *(short8*)((char*)l + b) = v;
    }
}
template<int KW8>
static __device__ inline short8 rdfrag(const ushort_t* l, int row, int kg) {
    int b = (row * (KW8 * 16) + kg * 16) ^ ((row & 7) << 4);
    return *(const short8*)((const char*)l + b);
}
// A-frag straight from global (row-major, LD shorts per row)
static __device__ inline short8 afrag(const ushort_t* base, int LD, int row, int kg) {
    return *(const short8*)(base + (size_t)row * LD + kg * 8);
}

// ---------------------------------------------------------------------------
// split / transpose-split pre-passes
__global__ __launch_bounds__(256) void split_x_kernel(
    const float* __restrict__ x, ushort_t* __restrict__ hi, ushort_t* __restrict__ lo)
{
    int idx = blockIdx.x * 256 + threadIdx.x;
    int total = M2 * 96;
    if (idx >= total) return;
    int row = idx / 96, c = idx - row * 96;
    float v = (row < N_NODES && c < F) ? x[(size_t)row * F + c] : 0.f;
    split_store(hi, lo, idx, v);
}

// generic: src fp32 [K][N] row-major -> Bt [N][Kpad] bf16 hi/lo (zero-pad k>=K)
__global__ __launch_bounds__(256) void tsplit_kernel(
    const float* __restrict__ src, int K, int Kpad, int N,
    ushort_t* __restrict__ hi, ushort_t* __restrict__ lo)
{
    int idx = blockIdx.x * 256 + threadIdx.x;
    if (idx >= N * Kpad) return;
    int col = idx / Kpad, k = idx - col * Kpad;
    float v = (k < K) ? src[(size_t)k * N + col] : 0.f;
    split_store(hi, lo, idx, v);
}

// edge_W [T][H][H] -> Bt [256][64]: Bt[c][k] = edge_W[c>>6][k][c&63]
__global__ __launch_bounds__(256) void tsplit_edge_kernel(
    const float* __restrict__ eW, ushort_t* __restrict__ hi, ushort_t* __restrict__ lo)
{
    int idx = blockIdx.x * 256 + threadIdx.x;
    if (idx >= 256 * 64) return;
    int c = idx >> 6, k = idx & 63;
    float v = eW[(c >> 6) * 4096 + k * 64 + (c & 63)];
    split_store(hi, lo, idx, v);
}

// gru: Btg [2][96][128]; half hh, col c: gate gg=c>>5, oo=hh*32+(c&31)
// k<64 -> Wih[k][gg*64+oo], k>=64 -> Whh[k-64][gg*64+oo]
__global__ __launch_bounds__(256) void tsplit_gru_kernel(
    const float* __restrict__ Wih, const float* __restrict__ Whh,
    ushort_t* __restrict__ hi, ushort_t* __restrict__ lo)
{
    int idx = blockIdx.x * 256 + threadIdx.x;
    if (idx >= 2 * 96 * 128) return;
    int hh = idx / (96 * 128);
    int r  = idx - hh * (96 * 128);
    int c = r >> 7, k = r & 127;
    int gg = c >> 5, oo = hh * 32 + (c & 31);
    int col = gg * 64 + oo;
    float v = (k < 64) ? Wih[(size_t)k * 192 + col] : Whh[(size_t)(k - 64) * 192 + col];
    split_store(hi, lo, idx, v);
}

// ---------------------------------------------------------------------------
// CSR build (unchanged from round 3)
__global__ __launch_bounds__(256) void deg_kernel(
    const int* __restrict__ dst, int* __restrict__ deg)
{
    int e = blockIdx.x * 256 + threadIdx.x;
    if (e < N_EDGES) atomicAdd(&deg[dst[e]], 1);
}

__global__ __launch_bounds__(1024) void scan_kernel(
    const int* __restrict__ deg, int* __restrict__ row_ptr, int* __restrict__ cursor)
{
    __shared__ int wsum[16];
    __shared__ int wpre[16];
    __shared__ int btot;
    const int tid = threadIdx.x;
    const int lane = tid & 63;
    const int w = tid >> 6;
    int running = 0;
    for (int base = 0; base < N_NODES; base += 1024) {
        int idx = base + tid;
        int v = (idx < N_NODES) ? deg[idx] : 0;
        int x = v;
#pragma unroll
        for (int off = 1; off < 64; off <<= 1) {
            int u = __shfl_up(x, off, 64);
            if (lane >= off) x += u;
        }
        if (lane == 63) wsum[w] = x;
        __syncthreads();
        if (w == 0) {
            int s = (lane < 16) ? wsum[lane & 15] : 0;
#pragma unroll
            for (int off = 1; off < 16; off <<= 1) {
                int u = __shfl_up(s, off, 64);
                if (lane >= off) s += u;
            }
            if (lane < 16) wpre[lane] = s - wsum[lane];
            if (lane == 15) btot = s;
        }
        __syncthreads();
        int excl = running + wpre[w] + (x - v);
        if (idx < N_NODES) { row_ptr[idx] = excl; cursor[idx] = excl; }
        running += btot;
        __syncthreads();
    }
    if (tid == 0) row_ptr[N_NODES] = running;
}

__global__ __launch_bounds__(256) void fill_kernel(
    const int* __restrict__ src, const int* __restrict__ etype,
    const int* __restrict__ dst, int* __restrict__ cursor, int* __restrict__ ss)
{
    int e = blockIdx.x * 256 + threadIdx.x;
    if (e < N_EDGES) {
        int p = atomicAdd(&cursor[dst[e]], 1);
        ss[p] = src[e] * 4 + etype[e];
    }
}

// ---------------------------------------------------------------------------
// init: C = x @ W_in + b_in ;  A = x_hi/lo [M2][96], B = BtWin [64][96]
// writes cat.h (cols 64..127 of cat) and hinit arrays
__global__ __launch_bounds__(256) void init_gemm(
    const ushort_t* __restrict__ xhi, const ushort_t* __restrict__ xlo,
    const ushort_t* __restrict__ Bh, const ushort_t* __restrict__ Bl,
    const float* __restrict__ b_in,
    ushort_t* __restrict__ cat_hi, ushort_t* __restrict__ cat_lo,
    ushort_t* __restrict__ hin_hi, ushort_t* __restrict__ hin_lo)
{
    __shared__ ushort_t lds[12288];
    ushort_t* LBh = lds;
    ushort_t* LBl = lds + 6144;
    const int tid = threadIdx.x, lane = tid & 63, wid = tid >> 6;
    const int lr = lane & 15, g = lane >> 4;
    stage_tile<12>(Bh, LBh, 64, tid);
    stage_tile<12>(Bl, LBl, 64, tid);
    __syncthreads();
    for (int wt = blockIdx.x * 4 + wid; wt < NTILES16; wt += gridDim.x * 4) {
        const ushort_t* pAh = xhi + (size_t)wt * 16 * 96;
        const ushort_t* pAl = xlo + (size_t)wt * 16 * 96;
        f32x4 acc[4];
        f32x4 zz = {0.f, 0.f, 0.f, 0.f};
#pragma unroll
        for (int f = 0; f < 4; ++f) acc[f] = zz;
#pragma unroll
        for (int ks = 0; ks < 3; ++ks) {
            int kg = ks * 4 + g;
            short8 ah = afrag(pAh, 96, lr, kg);
            short8 al = afrag(pAl, 96, lr, kg);
#pragma unroll
            for (int f = 0; f < 4; ++f) {
                short8 bh = rdfrag<12>(LBh, f * 16 + lr, kg);
                short8 bl = rdfrag<12>(LBl, f * 16 + lr, kg);
                acc[f] = MFMA(ah, bh, acc[f]);
                acc[f] = MFMA(ah, bl, acc[f]);
                acc[f] = MFMA(al, bh, acc[f]);
            }
        }
#pragma unroll
        for (int f = 0; f < 4; ++f) {
            int o = lr + f * 16;
            float b = b_in[o];
#pragma unroll
            for (int q = 0; q < 4; ++q) {
                int m = wt * 16 + g * 4 + q;
                if (m < N_NODES) {
                    float v = acc[f][q] + b;
                    split_store(cat_hi, cat_lo, (size_t)m * 128 + 64 + o, v);
                    split_store(hin_hi, hin_lo, (size_t)m * 64 + o, v);
                }
            }
        }
    }
}

// ---------------------------------------------------------------------------
// nt: ntr[m, coff+c] = relu( h @ edge_W + edge_b ), 128 cols per dispatch
// A = cat.h (LD=128, ptr pre-offset +64), B = BtE slice [128][64]
__global__ __launch_bounds__(256) void nt_gemm(
    const ushort_t* __restrict__ ahi, const ushort_t* __restrict__ alo,
    const ushort_t* __restrict__ Bh, const ushort_t* __restrict__ Bl,
    const float* __restrict__ edge_b, ushort_t* __restrict__ ntr, int coff)
{
    __shared__ ushort_t lds[16384];
    ushort_t* LBh = lds;
    ushort_t* LBl = lds + 8192;
    const int tid = threadIdx.x, lane = tid & 63, wid = tid >> 6;
    const int lr = lane & 15, g = lane >> 4;
    stage_tile<8>(Bh, LBh, 128, tid);
    stage_tile<8>(Bl, LBl, 128, tid);
    __syncthreads();
    for (int wt = blockIdx.x * 4 + wid; wt < NTILES16; wt += gridDim.x * 4) {
        const ushort_t* pAh = ahi + (size_t)wt * 16 * 128;
        const ushort_t* pAl = alo + (size_t)wt * 16 * 128;
        f32x4 acc[8];
        f32x4 zz = {0.f, 0.f, 0.f, 0.f};
#pragma unroll
        for (int f = 0; f < 8; ++f) acc[f] = zz;
#pragma unroll
        for (int ks = 0; ks < 2; ++ks) {
            int kg = ks * 4 + g;
            short8 ah = afrag(pAh, 128, lr, kg);
            short8 al = afrag(pAl, 128, lr, kg);
#pragma unroll
            for (int f = 0; f < 8; ++f) {
                short8 bh = rdfrag<8>(LBh, f * 16 + lr, kg);
                short8 bl = rdfrag<8>(LBl, f * 16 + lr, kg);
                acc[f] = MFMA(ah, bh, acc[f]);
                acc[f] = MFMA(ah, bl, acc[f]);
                acc[f] = MFMA(al, bh, acc[f]);
            }
        }
#pragma unroll
        for (int f = 0; f < 8; ++f) {
            int colg = coff + lr + f * 16;
            float b = edge_b[colg >> 6];
#pragma unroll
            for (int q = 0; q < 4; ++q) {
                int m = wt * 16 + g * 4 + q;
                if (m < N_NODES) {
                    float v = fmaxf(acc[f][q] + b, 0.f);
                    ntr[(size_t)m * 256 + colg] = f2b(v);
                }
            }
        }
    }
}

// ---------------------------------------------------------------------------
// agg: cat.agg[d] = sum_{incoming e} ntr[rec_e]  (wave per dst node)
__global__ __launch_bounds__(256) void agg_kernel(
    const ushort_t* __restrict__ ntr, const int* __restrict__ row_ptr,
    const int* __restrict__ ss, ushort_t* __restrict__ cat_hi,
    ushort_t* __restrict__ cat_lo)
{
    const int lane = threadIdx.x & 63;
    const int w = __builtin_amdgcn_readfirstlane((int)(threadIdx.x >> 6));
    const int d = blockIdx.x * 4 + w;
    if (d >= N_NODES) return;
    const int beg = row_ptr[d];
    const int end = row_ptr[d + 1];
    float acc = 0.f;
    int p = beg;
    for (; p + 8 <= end; p += 8) {
        int r0 = ss[p + 0], r1 = ss[p + 1], r2 = ss[p + 2], r3 = ss[p + 3];
        int r4 = ss[p + 4], r5 = ss[p + 5], r6 = ss[p + 6], r7 = ss[p + 7];
        float v0 = b2f(ntr[(size_t)r0 * 64 + lane]);
        float v1 = b2f(ntr[(size_t)r1 * 64 + lane]);
        float v2 = b2f(ntr[(size_t)r2 * 64 + lane]);
        float v3 = b2f(ntr[(size_t)r3 * 64 + lane]);
        float v4 = b2f(ntr[(size_t)r4 * 64 + lane]);
        float v5 = b2f(ntr[(size_t)r5 * 64 + lane]);
        float v6 = b2f(ntr[(size_t)r6 * 64 + lane]);
        float v7 = b2f(ntr[(size_t)r7 * 64 + lane]);
        acc += ((v0 + v1) + (v2 + v3)) + ((v4 + v5) + (v6 + v7));
    }
    for (; p < end; ++p)
        acc += b2f(ntr[(size_t)ss[p] * 64 + lane]);
    split_store(cat_hi, cat_lo, (size_t)d * 128 + lane, acc);
}

// ---------------------------------------------------------------------------
// gru: 32 output cols per dispatch (ooff = hh*32).
// A = catX [M2][128] = [agg|h]; B = Btg96 slice [96][128] (cols r,z,n fused-K)
// n-gate: ks<2 (agg part) -> aIN, ks>=2 (h part) -> aHN.
__global__ __launch_bounds__(256) void gru_gemm(
    const ushort_t* __restrict__ catXhi, const ushort_t* __restrict__ catXlo,
    const ushort_t* __restrict__ Bh, const ushort_t* __restrict__ Bl,
    const float* __restrict__ bih, const float* __restrict__ bhh,
    ushort_t* __restrict__ catYhi, ushort_t* __restrict__ catYlo, int ooff)
{
    __shared__ ushort_t lds[24576];
    ushort_t* LBh = lds;
    ushort_t* LBl = lds + 12288;
    const int tid = threadIdx.x, lane = tid & 63, wid = tid >> 6;
    const int lr = lane & 15, g = lane >> 4;
    stage_tile<16>(Bh, LBh, 96, tid);
    stage_tile<16>(Bl, LBl, 96, tid);
    __syncthreads();
    for (int wt = blockIdx.x * 4 + wid; wt < NTILES16; wt += gridDim.x * 4) {
        const ushort_t* pAh = catXhi + (size_t)wt * 16 * 128;
        const ushort_t* pAl = catXlo + (size_t)wt * 16 * 128;
        f32x4 acc[4], aIN[2], aHN[2];
        f32x4 zz = {0.f, 0.f, 0.f, 0.f};
#pragma unroll
        for (int f = 0; f < 4; ++f) acc[f] = zz;
        aIN[0] = zz; aIN[1] = zz; aHN[0] = zz; aHN[1] = zz;
#pragma unroll
        for (int ks = 0; ks < 4; ++ks) {
            int kg = ks * 4 + g;
            short8 ah = afrag(pAh, 128, lr, kg);
            short8 al = afrag(pAl, 128, lr, kg);
#pragma unroll
            for (int f = 0; f < 6; ++f) {
                short8 bh = rdfrag<16>(LBh, f * 16 + lr, kg);
                short8 bl = rdfrag<16>(LBl, f * 16 + lr, kg);
                if (f < 4) {
                    acc[f] = MFMA(ah, bh, acc[f]);
                    acc[f] = MFMA(ah, bl, acc[f]);
                    acc[f] = MFMA(al, bh, acc[f]);
                } else if (ks < 2) {
                    aIN[f - 4] = MFMA(ah, bh, aIN[f - 4]);
                    aIN[f - 4] = MFMA(ah, bl, aIN[f - 4]);
                    aIN[f - 4] = MFMA(al, bh, aIN[f - 4]);
                } else {
                    aHN[f - 4] = MFMA(ah, bh, aHN[f - 4]);
                    aHN[f - 4] = MFMA(ah, bl, aHN[f - 4]);
                    aHN[f - 4] = MFMA(al, bh, aHN[f - 4]);
                }
            }
        }
#pragma unroll
        for (int fr = 0; fr < 2; ++fr) {
            int o = ooff + fr * 16 + lr;
            float br = bih[o] + bhh[o];
            float bz = bih[64 + o] + bhh[64 + o];
            float bi_n = bih[128 + o];
            float bh_n = bhh[128 + o];
#pragma unroll
            for (int q = 0; q < 4; ++q) {
                int m = wt * 16 + g * 4 + q;
                if (m < N_NODES) {
                    float r = sigm(acc[fr][q] + br);
                    float z = sigm(acc[2 + fr][q] + bz);
                    float inn = aIN[fr][q] + bi_n;
                    float hn = aHN[fr][q] + bh_n;
                    float nn = tanh_f(inn + r * hn);
                    size_t hix = (size_t)m * 128 + 64 + o;
                    float hp = b2f(catXhi[hix]) + b2f(catXlo[hix]);
                    float hv = (1.f - z) * nn + z * hp;
                    split_store(catYhi, catYlo, hix, hv);
                }
            }
        }
    }
}

// ---------------------------------------------------------------------------
// mlp1: hidden = relu([hinit, h] @ W1 + b1); K=128 (2 parts), N=64
__global__ __launch_bounds__(256) void mlp1_gemm(
    const ushort_t* __restrict__ hin_hi, const ushort_t* __restrict__ hin_lo,
    const ushort_t* __restrict__ cathi, const ushort_t* __restrict__ catlo, // +64 pre-offset
    const ushort_t* __restrict__ Bh, const ushort_t* __restrict__ Bl,
    const float* __restrict__ b1,
    ushort_t* __restrict__ hid_hi, ushort_t* __restrict__ hid_lo)
{
    __shared__ ushort_t lds[16384];
    ushort_t* LBh = lds;
    ushort_t* LBl = lds + 8192;
    const int tid = threadIdx.x, lane = tid & 63, wid = tid >> 6;
    const int lr = lane & 15, g = lane >> 4;
    stage_tile<16>(Bh, LBh, 64, tid);
    stage_tile<16>(Bl, LBl, 64, tid);
    __syncthreads();
    for (int wt = blockIdx.x * 4 + wid; wt < NTILES16; wt += gridDim.x * 4) {
        const ushort_t* pAh0 = hin_hi + (size_t)wt * 16 * 64;
        const ushort_t* pAl0 = hin_lo + (size_t)wt * 16 * 64;
        const ushort_t* pAh1 = cathi + (size_t)wt * 16 * 128;
        const ushort_t* pAl1 = catlo + (size_t)wt * 16 * 128;
        f32x4 acc[4];
        f32x4 zz = {0.f, 0.f, 0.f, 0.f};
#pragma unroll
        for (int f = 0; f < 4; ++f) acc[f] = zz;
#pragma unroll
        for (int ks = 0; ks < 4; ++ks) {
            int kg = ks * 4 + g;
            short8 ah, al;
            if (ks < 2) {
                ah = afrag(pAh0, 64, lr, kg);
                al = afrag(pAl0, 64, lr, kg);
            } else {
                ah = afrag(pAh1, 128, lr, (ks - 2) * 4 + g);
                al = afrag(pAl1, 128, lr, (ks - 2) * 4 + g);
            }
#pragma unroll
            for (int f = 0; f < 4; ++f) {
                short8 bh = rdfrag<16>(LBh, f * 16 + lr, kg);
                short8 bl = rdfrag<16>(LBl, f * 16 + lr, kg);
                acc[f] = MFMA(ah, bh, acc[f]);
                acc[f] = MFMA(ah, bl, acc[f]);
                acc[f] = MFMA(al, bh, acc[f]);
            }
        }
#pragma unroll
        for (int f = 0; f < 4; ++f) {
            int o = lr + f * 16;
            float b = b1[o];
#pragma unroll
            for (int q = 0; q < 4; ++q) {
                int m = wt * 16 + g * 4 + q;
                if (m < N_NODES) {
                    float v = fmaxf(acc[f][q] + b, 0.f);
                    split_store(hid_hi, hid_lo, (size_t)m * 64 + o, v);
                }
            }
        }
    }
}

// mlp2: out = tanh(hidden @ W2 + b2)
__global__ __launch_bounds__(256) void mlp2_gemm(
    const ushort_t* __restrict__ hid_hi, const ushort_t* __restrict__ hid_lo,
    const ushort_t* __restrict__ Bh, const ushort_t* __restrict__ Bl,
    const float* __restrict__ b2, float* __restrict__ out)
{
    __shared__ ushort_t lds[8192];
    ushort_t* LBh = lds;
    ushort_t* LBl = lds + 4096;
    const int tid = threadIdx.x, lane = tid & 63, wid = tid >> 6;
    const int lr = lane & 15, g = lane >> 4;
    stage_tile<8>(Bh, LBh, 64, tid);
    stage_tile<8>(Bl, LBl, 64, tid);
    __syncthreads();
    for (int wt = blockIdx.x * 4 + wid; wt < NTILES16; wt += gridDim.x * 4) {
        const ushort_t* pAh = hid_hi + (size_t)wt * 16 * 64;
        const ushort_t* pAl = hid_lo + (size_t)wt * 16 * 64;
        f32x4 acc[4];
        f32x4 zz = {0.f, 0.f, 0.f, 0.f};
#pragma unroll
        for (int f = 0; f < 4; ++f) acc[f] = zz;
#pragma unroll
        for (int ks = 0; ks < 2; ++ks) {
            int kg = ks * 4 + g;
            short8 ah = afrag(pAh, 64, lr, kg);
            short8 al = afrag(pAl, 64, lr, kg);
#pragma unroll
            for (int f = 0; f < 4; ++f) {
                short8 bh = rdfrag<8>(LBh, f * 16 + lr, kg);
                short8 bl = rdfrag<8>(LBl, f * 16 + lr, kg);
                acc[f] = MFMA(ah, bh, acc[f]);
                acc[f] = MFMA(ah, bl, acc[f]);
                acc[f] = MFMA(al, bh, acc[f]);
            }
        }
#pragma unroll
        for (int f = 0; f < 4; ++f) {
            int o = lr + f * 16;
            float b = b2[o];
#pragma unroll
            for (int q = 0; q < 4; ++q) {
                int m = wt * 16 + g * 4 + q;
                if (m < N_NODES)
                    out[(size_t)m * 64 + o] = tanh_f(acc[f][q] + b);
            }
        }
    }
}

// ---------------------------------------------------------------------------
extern "C" void kernel_launch(void* const* d_in, const int* in_sizes, int n_in,
                              void* d_out, int out_size, void* d_ws, size_t ws_size,
                              hipStream_t stream)
{
    const float* x      = (const float*)d_in[0];
    const int*   etype  = (const int*)  d_in[1];
    const int*   src    = (const int*)  d_in[2];
    const int*   dst    = (const int*)  d_in[3];
    const float* W_in   = (const float*)d_in[4];
    const float* b_in   = (const float*)d_in[5];
    const float* edge_W = (const float*)d_in[6];
    const float* edge_b = (const float*)d_in[7];
    const float* gWih   = (const float*)d_in[8];
    const float* gWhh   = (const float*)d_in[9];
    const float* gbih   = (const float*)d_in[10];
    const float* gbhh   = (const float*)d_in[11];
    const float* W1     = (const float*)d_in[12];
    const float* b1     = (const float*)d_in[13];
    const float* W2     = (const float*)d_in[14];
    const float* b2     = (const float*)d_in[15];
    float* out = (float*)d_out;

    char* ws = (char*)d_ws;
    // --- workspace layout (bytes) ---
    ushort_t* ntr     = (ushort_t*)(ws);                        // M2*256*2 = 25,624,576
    ushort_t* x_hi    = (ushort_t*)(ws);                        // alias (init only)
    ushort_t* x_lo    = (ushort_t*)(ws + 9609216);
    ushort_t* hid_hi  = (ushort_t*)(ws);                        // alias (post-ntr)
    ushort_t* hid_lo  = (ushort_t*)(ws + 6406144);
    ushort_t* catA_hi = (ushort_t*)(ws + 25624576);             // each 12,812,288
    ushort_t* catA_lo = (ushort_t*)(ws + 38436864);
    ushort_t* catB_hi = (ushort_t*)(ws + 51249152);
    ushort_t* catB_lo = (ushort_t*)(ws + 64061440);
    ushort_t* hin_hi  = (ushort_t*)(ws + 76873728);             // each 6,406,144
    ushort_t* hin_lo  = (ushort_t*)(ws + 83279872);
    char* wbase = ws + 89686016;
    ushort_t* BtWin_hi = (ushort_t*)(wbase);                    // 64*96*2
    ushort_t* BtWin_lo = (ushort_t*)(wbase + 12288);
    ushort_t* BtE_hi   = (ushort_t*)(wbase + 24576);            // 256*64*2
    ushort_t* BtE_lo   = (ushort_t*)(wbase + 57344);
    ushort_t* Btg_hi   = (ushort_t*)(wbase + 90112);            // 2*96*128*2
    ushort_t* Btg_lo   = (ushort_t*)(wbase + 139264);
    ushort_t* BtW1_hi  = (ushort_t*)(wbase + 188416);           // 64*128*2
    ushort_t* BtW1_lo  = (ushort_t*)(wbase + 204800);
    ushort_t* BtW2_hi  = (ushort_t*)(wbase + 221184);           // 64*64*2
    ushort_t* BtW2_lo  = (ushort_t*)(wbase + 229376);
    char* cbase = ws + 89948160;
    int* deg    = (int*)(cbase);
    int* rowp   = (int*)(cbase + 200192);
    int* cursor = (int*)(cbase + 400384);
    int* ss     = (int*)(cbase + 600576);

    const int edge_tblocks = (N_EDGES + 255) / 256;
    const int agg_blocks = (N_NODES + 3) / 4;
    const int GB = 782;   // GEMM grid: 782*4 waves = 3128 = NTILES16

    // CSR build
    hipMemsetAsync(deg, 0, N_NODES * sizeof(int), stream);
    deg_kernel<<<edge_tblocks, 256, 0, stream>>>(dst, deg);
    scan_kernel<<<1, 1024, 0, stream>>>(deg, rowp, cursor);
    fill_kernel<<<edge_tblocks, 256, 0, stream>>>(src, etype, dst, cursor, ss);

    // splits
    split_x_kernel<<<(M2 * 96 + 255) / 256, 256, 0, stream>>>(x, x_hi, x_lo);
    tsplit_kernel<<<(64 * 96 + 255) / 256, 256, 0, stream>>>(W_in, F, 96, 64, BtWin_hi, BtWin_lo);
    tsplit_edge_kernel<<<(256 * 64 + 255) / 256, 256, 0, stream>>>(edge_W, BtE_hi, BtE_lo);
    tsplit_gru_kernel<<<(2 * 96 * 128 + 255) / 256, 256, 0, stream>>>(gWih, gWhh, Btg_hi, Btg_lo);
    tsplit_kernel<<<(64 * 128 + 255) / 256, 256, 0, stream>>>(W1, 128, 128, 64, BtW1_hi, BtW1_lo);
    tsplit_kernel<<<(64 * 64 + 255) / 256, 256, 0, stream>>>(W2, 64, 64, 64, BtW2_hi, BtW2_lo);

    // init -> catA.h + hinit
    init_gemm<<<GB, 256, 0, stream>>>(x_hi, x_lo, BtWin_hi, BtWin_lo, b_in,
                                      catA_hi, catA_lo, hin_hi, hin_lo);

    ushort_t *Xhi = catA_hi, *Xlo = catA_lo, *Yhi = catB_hi, *Ylo = catB_lo;
    for (int s = 0; s < STEPS; ++s) {
        nt_gemm<<<GB, 256, 0, stream>>>(Xhi + 64, Xlo + 64, BtE_hi, BtE_lo,
                                        edge_b, ntr, 0);
        nt_gemm<<<GB, 256, 0, stream>>>(Xhi + 64, Xlo + 64, BtE_hi + 8192, BtE_lo + 8192,
                                        edge_b, ntr, 128);
        agg_kernel<<<agg_blocks, 256, 0, stream>>>(ntr, rowp, ss, Xhi, Xlo);
        gru_gemm<<<GB, 256, 0, stream>>>(Xhi, Xlo, Btg_hi, Btg_lo, gbih, gbhh,
                                         Yhi, Ylo, 0);
        gru_gemm<<<GB, 256, 0, stream>>>(Xhi, Xlo, Btg_hi + 12288, Btg_lo + 12288,
                                         gbih, gbhh, Yhi, Ylo, 32);
        ushort_t* t;
        t = Xhi; Xhi = Yhi; Yhi = t;
        t = Xlo; Xlo = Ylo; Ylo = t;
    }
    // after 4 steps final h is in catA (Xhi == catA_hi)

    mlp1_gemm<<<GB, 256, 0, stream>>>(hin_hi, hin_lo, Xhi + 64, Xlo + 64,
                                      BtW1_hi, BtW1_lo, b1, hid_hi, hid_lo);
    mlp2_gemm<<<GB, 256, 0, stream>>>(hid_hi, hid_lo, BtW2_hi, BtW2_lo, b2, out);
}

// Round 5
// 536.864 us; speedup vs baseline: 3.5607x; 1.1133x over previous
//
#include <hip/hip_runtime.h>
#include <hip/hip_bf16.h>

#define N_NODES 50000
#define M2      50048          // padded to multiple of 64
#define N_EDGES 800000
#define H 64
#define F 74
#define T 4
#define STEPS 4
#define NTILES16 (M2/16)       // 3128 wave-tiles of 16 rows
#define PAD_REC  (M2*4)        // zeroed pad row in ntr
#define SCAN_NB  196           // ceil(N_NODES/256)

using short8 = __attribute__((ext_vector_type(8))) short;
using f32x4  = __attribute__((ext_vector_type(4))) float;
typedef unsigned short ushort_t;

#define MFMA(a,b,c) __builtin_amdgcn_mfma_f32_16x16x32_bf16(a,b,c,0,0,0)

static __device__ inline float b2f(ushort_t u) {
    union { unsigned int i; float f; } c; c.i = ((unsigned int)u) << 16; return c.f;
}
static __device__ inline ushort_t f2b(float v) {
    union { __hip_bfloat16 b; ushort_t u; } c; c.b = __float2bfloat16(v); return c.u;
}
static __device__ inline void split_store(ushort_t* hi, ushort_t* lo, size_t ix, float v) {
    ushort_t h = f2b(v);
    hi[ix] = h;
    lo[ix] = f2b(v - b2f(h));
}
static __device__ inline float sigm(float x) { return 1.f / (1.f + __expf(-x)); }
static __device__ inline float tanh_f(float x) {
    float e2 = __expf(2.f * x); return 1.f - 2.f / (e2 + 1.f);
}

// ---- LDS staging of B-tiles (bf16, row-major [rows][KW8*8]) with XOR swizzle
template<int KW8>
static __device__ inline void stage_tile(const ushort_t* __restrict__ g, ushort_t* l,
                                         int rows, int tid) {
    const int chunks = rows * KW8;
    for (int i = tid; i < chunks; i += 256) {
        int row = i / KW8, kg = i - row * KW8;
        short8 v = *(const short8*)(g + (size_t)row * (KW8 * 8) + kg * 8);
        int b = (row * (KW8 * 16) + kg * 16) ^ ((row & 7) << 4);
        *(short8*)((char*)l + b) = v;
    }
}
template<int KW8>
static __device__ inline short8 rdfrag(const ushort_t* l, int row, int kg) {
    int b = (row * (KW8 * 16) + kg * 16) ^ ((row & 7) << 4);
    return *(const short8*)((const char*)l + b);
}
static __device__ inline short8 afrag(const ushort_t* base, int LD, int row, int kg) {
    return *(const short8*)(base + (size_t)row * LD + kg * 8);
}

// ---------------------------------------------------------------------------
// split x into hi/lo bf16 [M2][96]
__global__ __launch_bounds__(256) void split_x_kernel(
    const float* __restrict__ x, ushort_t* __restrict__ hi, ushort_t* __restrict__ lo)
{
    int idx = blockIdx.x * 256 + threadIdx.x;
    int total = M2 * 96;
    if (idx >= total) return;
    int row = idx / 96, c = idx - row * 96;
    float v = (row < N_NODES && c < F) ? x[(size_t)row * F + c] : 0.f;
    split_store(hi, lo, idx, v);
}

// ---------------------------------------------------------------------------
// fused weight prep: all B^T transforms in one dispatch.
// ranges: [0,6144) Win | [6144,22528) E(hi only) | [22528,47104) gru |
//         [47104,55296) W1 | [55296,59392) W2
__global__ __launch_bounds__(256) void prep_w_kernel(
    const float* __restrict__ W_in, const float* __restrict__ eW,
    const float* __restrict__ Wih, const float* __restrict__ Whh,
    const float* __restrict__ W1, const float* __restrict__ W2,
    ushort_t* __restrict__ BtWin_hi, ushort_t* __restrict__ BtWin_lo,
    ushort_t* __restrict__ BtE_hi,
    ushort_t* __restrict__ Btg_hi, ushort_t* __restrict__ Btg_lo,
    ushort_t* __restrict__ BtW1_hi, ushort_t* __restrict__ BtW1_lo,
    ushort_t* __restrict__ BtW2_hi, ushort_t* __restrict__ BtW2_lo)
{
    int idx = blockIdx.x * 256 + threadIdx.x;
    if (idx < 6144) {                       // Win: [64 col][96 k]
        int col = idx / 96, k = idx - col * 96;
        float v = (k < F) ? W_in[(size_t)k * 64 + col] : 0.f;
        split_store(BtWin_hi, BtWin_lo, idx, v);
    } else if (idx < 22528) {               // E: [256 c][64 k], hi only
        int i = idx - 6144;
        int c = i >> 6, k = i & 63;
        float v = eW[(c >> 6) * 4096 + k * 64 + (c & 63)];
        BtE_hi[i] = f2b(v);
    } else if (idx < 47104) {               // gru: [2 hh][96 c][128 k]
        int i = idx - 22528;
        int hh = i / (96 * 128);
        int r = i - hh * (96 * 128);
        int c = r >> 7, k = r & 127;
        int gg = c >> 5, oo = hh * 32 + (c & 31);
        int col = gg * 64 + oo;
        float v = (k < 64) ? Wih[(size_t)k * 192 + col]
                           : Whh[(size_t)(k - 64) * 192 + col];
        split_store(Btg_hi, Btg_lo, i, v);
    } else if (idx < 55296) {               // W1: [64 col][128 k]
        int i = idx - 47104;
        int col = i >> 7, k = i & 127;
        float v = W1[(size_t)k * 64 + col];
        split_store(BtW1_hi, BtW1_lo, i, v);
    } else if (idx < 59392) {               // W2: [64 col][64 k]
        int i = idx - 55296;
        int col = i >> 6, k = i & 63;
        float v = W2[(size_t)k * 64 + col];
        split_store(BtW2_hi, BtW2_lo, i, v);
    }
}

// ---------------------------------------------------------------------------
// CSR build
__global__ __launch_bounds__(256) void deg_kernel(
    const int* __restrict__ dst, int* __restrict__ deg)
{
    int e = blockIdx.x * 256 + threadIdx.x;
    if (e < N_EDGES) atomicAdd(&deg[dst[e]], 1);
}

// pass 1: per-block (256 elems) sums
__global__ __launch_bounds__(256) void scan_p1(
    const int* __restrict__ deg, int* __restrict__ bsum)
{
    __shared__ int ws4[4];
    const int tid = threadIdx.x, lane = tid & 63, w = tid >> 6;
    int idx = blockIdx.x * 256 + tid;
    int v = (idx < N_NODES) ? deg[idx] : 0;
#pragma unroll
    for (int off = 32; off >= 1; off >>= 1) v += __shfl_down(v, off, 64);
    if (lane == 0) ws4[w] = v;
    __syncthreads();
    if (tid == 0) bsum[blockIdx.x] = ws4[0] + ws4[1] + ws4[2] + ws4[3];
}

// pass 2: single block exclusive scan of SCAN_NB block sums
__global__ __launch_bounds__(256) void scan_p2(
    const int* __restrict__ bsum, int* __restrict__ boff, int* __restrict__ rowp)
{
    __shared__ int ws4[4];
    const int tid = threadIdx.x, lane = tid & 63, w = tid >> 6;
    int v = (tid < SCAN_NB) ? bsum[tid] : 0;
    int x = v;
#pragma unroll
    for (int off = 1; off < 64; off <<= 1) {
        int u = __shfl_up(x, off, 64);
        if (lane >= off) x += u;
    }
    if (lane == 63) ws4[w] = x;
    __syncthreads();
    int a0 = ws4[0], a1 = ws4[1], a2 = ws4[2];
    int add = (w > 0 ? a0 : 0) + (w > 1 ? a1 : 0) + (w > 2 ? a2 : 0);
    if (tid < SCAN_NB) boff[tid] = add + x - v;
    if (tid == 255) rowp[N_NODES] = add + x;
}

// pass 3: local exclusive scan + block offset -> rowp, cursor
__global__ __launch_bounds__(256) void scan_p3(
    const int* __restrict__ deg, const int* __restrict__ boff,
    int* __restrict__ rowp, int* __restrict__ cursor)
{
    __shared__ int ws4[4];
    const int tid = threadIdx.x, lane = tid & 63, w = tid >> 6;
    int idx = blockIdx.x * 256 + tid;
    int v = (idx < N_NODES) ? deg[idx] : 0;
    int x = v;
#pragma unroll
    for (int off = 1; off < 64; off <<= 1) {
        int u = __shfl_up(x, off, 64);
        if (lane >= off) x += u;
    }
    if (lane == 63) ws4[w] = x;
    __syncthreads();
    int a0 = ws4[0], a1 = ws4[1], a2 = ws4[2];
    int add = boff[blockIdx.x]
            + (w > 0 ? a0 : 0) + (w > 1 ? a1 : 0) + (w > 2 ? a2 : 0);
    int excl = add + x - v;
    if (idx < N_NODES) { rowp[idx] = excl; cursor[idx] = excl; }
}

__global__ __launch_bounds__(256) void fill_kernel(
    const int* __restrict__ src, const int* __restrict__ etype,
    const int* __restrict__ dst, int* __restrict__ cursor, int* __restrict__ ss)
{
    int e = blockIdx.x * 256 + threadIdx.x;
    if (e < N_EDGES) {
        int p = atomicAdd(&cursor[dst[e]], 1);
        ss[p] = src[e] * 4 + etype[e];
    }
}

// ---------------------------------------------------------------------------
// init: C = x @ W_in + b_in  (full double-bf16, runs once)
__global__ __launch_bounds__(256) void init_gemm(
    const ushort_t* __restrict__ xhi, const ushort_t* __restrict__ xlo,
    const ushort_t* __restrict__ Bh, const ushort_t* __restrict__ Bl,
    const float* __restrict__ b_in,
    ushort_t* __restrict__ cat_hi, ushort_t* __restrict__ cat_lo,
    ushort_t* __restrict__ hin_hi, ushort_t* __restrict__ hin_lo)
{
    __shared__ ushort_t lds[12288];
    ushort_t* LBh = lds;
    ushort_t* LBl = lds + 6144;
    const int tid = threadIdx.x, lane = tid & 63, wid = tid >> 6;
    const int lr = lane & 15, g = lane >> 4;
    stage_tile<12>(Bh, LBh, 64, tid);
    stage_tile<12>(Bl, LBl, 64, tid);
    __syncthreads();
    for (int wt = blockIdx.x * 4 + wid; wt < NTILES16; wt += gridDim.x * 4) {
        const ushort_t* pAh = xhi + (size_t)wt * 16 * 96;
        const ushort_t* pAl = xlo + (size_t)wt * 16 * 96;
        f32x4 acc[4];
        f32x4 zz = {0.f, 0.f, 0.f, 0.f};
#pragma unroll
        for (int f = 0; f < 4; ++f) acc[f] = zz;
#pragma unroll
        for (int ks = 0; ks < 3; ++ks) {
            int kg = ks * 4 + g;
            short8 ah = afrag(pAh, 96, lr, kg);
            short8 al = afrag(pAl, 96, lr, kg);
#pragma unroll
            for (int f = 0; f < 4; ++f) {
                short8 bh = rdfrag<12>(LBh, f * 16 + lr, kg);
                short8 bl = rdfrag<12>(LBl, f * 16 + lr, kg);
                acc[f] = MFMA(ah, bh, acc[f]);
                acc[f] = MFMA(ah, bl, acc[f]);
                acc[f] = MFMA(al, bh, acc[f]);
            }
        }
#pragma unroll
        for (int f = 0; f < 4; ++f) {
            int o = lr + f * 16;
            float b = b_in[o];
#pragma unroll
            for (int q = 0; q < 4; ++q) {
                int m = wt * 16 + g * 4 + q;
                if (m < N_NODES) {
                    float v = acc[f][q] + b;
                    split_store(cat_hi, cat_lo, (size_t)m * 128 + 64 + o, v);
                    split_store(hin_hi, hin_lo, (size_t)m * 64 + o, v);
                }
            }
        }
    }
}

// ---------------------------------------------------------------------------
// nt (merged, single-bf16): ntr[m,c] = relu( h @ edge_W + edge_b ), all 256 cols.
// Output is truncated to bf16 anyway, so single-pass costs only sqrt(3)x error.
__global__ __launch_bounds__(256) void nt_gemm(
    const ushort_t* __restrict__ ahi,          // cat hi, pre-offset +64, LD=128
    const ushort_t* __restrict__ Bh,           // BtE_hi [256][64]
    const float* __restrict__ edge_b, ushort_t* __restrict__ ntr)
{
    __shared__ ushort_t lds[32768];            // 64 KB
    const int tid = threadIdx.x, lane = tid & 63, wid = tid >> 6;
    const int lr = lane & 15, g = lane >> 4;
    stage_tile<8>(Bh, lds, 256, tid);
    __syncthreads();
    for (int wt = blockIdx.x * 4 + wid; wt < NTILES16; wt += gridDim.x * 4) {
        const ushort_t* pAh = ahi + (size_t)wt * 16 * 128;
        f32x4 acc[16];
        f32x4 zz = {0.f, 0.f, 0.f, 0.f};
#pragma unroll
        for (int f = 0; f < 16; ++f) acc[f] = zz;
#pragma unroll
        for (int ks = 0; ks < 2; ++ks) {
            int kg = ks * 4 + g;
            short8 ah = afrag(pAh, 128, lr, kg);
#pragma unroll
            for (int f = 0; f < 16; ++f) {
                short8 bh = rdfrag<8>(lds, f * 16 + lr, kg);
                acc[f] = MFMA(ah, bh, acc[f]);
            }
        }
#pragma unroll
        for (int f = 0; f < 16; ++f) {
            int colg = lr + f * 16;
            float b = edge_b[colg >> 6];
#pragma unroll
            for (int q = 0; q < 4; ++q) {
                int m = wt * 16 + g * 4 + q;
                if (m < N_NODES) {
                    float v = fmaxf(acc[f][q] + b, 0.f);
                    ntr[(size_t)m * 256 + colg] = f2b(v);
                }
            }
        }
    }
}

// ---------------------------------------------------------------------------
// agg: branchless 16-wide gather batches; pad gathers hit the zeroed pad row.
__global__ __launch_bounds__(256, 4) void agg_kernel(
    const ushort_t* __restrict__ ntr, const int* __restrict__ row_ptr,
    const int* __restrict__ ss, ushort_t* __restrict__ cat_hi,
    ushort_t* __restrict__ cat_lo)
{
    const int lane = threadIdx.x & 63;
    const int w = __builtin_amdgcn_readfirstlane((int)(threadIdx.x >> 6));
    const int d = blockIdx.x * 4 + w;
    if (d >= N_NODES) return;
    const int beg = row_ptr[d];
    const int end = row_ptr[d + 1];
    float acc = 0.f;
    for (int p = beg; p < end; p += 16) {
        float v[16];
#pragma unroll
        for (int i = 0; i < 16; ++i) {
            bool inb = (p + i) < end;
            int rec = ss[inb ? (p + i) : beg];
            rec = inb ? rec : PAD_REC;
            v[i] = b2f(ntr[(size_t)rec * 64 + lane]);
        }
        float s0 = (v[0] + v[1]) + (v[2] + v[3]);
        float s1 = (v[4] + v[5]) + (v[6] + v[7]);
        float s2 = (v[8] + v[9]) + (v[10] + v[11]);
        float s3 = (v[12] + v[13]) + (v[14] + v[15]);
        acc += (s0 + s1) + (s2 + s3);
    }
    split_store(cat_hi, cat_lo, (size_t)d * 128 + lane, acc);
}

// ---------------------------------------------------------------------------
// gru (two dispatches of 32 output cols, full double-bf16)
__global__ __launch_bounds__(256) void gru_gemm(
    const ushort_t* __restrict__ catXhi, const ushort_t* __restrict__ catXlo,
    const ushort_t* __restrict__ Bh, const ushort_t* __restrict__ Bl,
    const float* __restrict__ bih, const float* __restrict__ bhh,
    ushort_t* __restrict__ catYhi, ushort_t* __restrict__ catYlo, int ooff)
{
    __shared__ ushort_t lds[24576];
    ushort_t* LBh = lds;
    ushort_t* LBl = lds + 12288;
    const int tid = threadIdx.x, lane = tid & 63, wid = tid >> 6;
    const int lr = lane & 15, g = lane >> 4;
    stage_tile<16>(Bh, LBh, 96, tid);
    stage_tile<16>(Bl, LBl, 96, tid);
    __syncthreads();
    for (int wt = blockIdx.x * 4 + wid; wt < NTILES16; wt += gridDim.x * 4) {
        const ushort_t* pAh = catXhi + (size_t)wt * 16 * 128;
        const ushort_t* pAl = catXlo + (size_t)wt * 16 * 128;
        f32x4 acc[4], aIN[2], aHN[2];
        f32x4 zz = {0.f, 0.f, 0.f, 0.f};
#pragma unroll
        for (int f = 0; f < 4; ++f) acc[f] = zz;
        aIN[0] = zz; aIN[1] = zz; aHN[0] = zz; aHN[1] = zz;
#pragma unroll
        for (int ks = 0; ks < 4; ++ks) {
            int kg = ks * 4 + g;
            short8 ah = afrag(pAh, 128, lr, kg);
            short8 al = afrag(pAl, 128, lr, kg);
#pragma unroll
            for (int f = 0; f < 6; ++f) {
                short8 bh = rdfrag<16>(LBh, f * 16 + lr, kg);
                short8 bl = rdfrag<16>(LBl, f * 16 + lr, kg);
                if (f < 4) {
                    acc[f] = MFMA(ah, bh, acc[f]);
                    acc[f] = MFMA(ah, bl, acc[f]);
                    acc[f] = MFMA(al, bh, acc[f]);
                } else if (ks < 2) {
                    aIN[f - 4] = MFMA(ah, bh, aIN[f - 4]);
                    aIN[f - 4] = MFMA(ah, bl, aIN[f - 4]);
                    aIN[f - 4] = MFMA(al, bh, aIN[f - 4]);
                } else {
                    aHN[f - 4] = MFMA(ah, bh, aHN[f - 4]);
                    aHN[f - 4] = MFMA(ah, bl, aHN[f - 4]);
                    aHN[f - 4] = MFMA(al, bh, aHN[f - 4]);
                }
            }
        }
#pragma unroll
        for (int fr = 0; fr < 2; ++fr) {
            int o = ooff + fr * 16 + lr;
            float br = bih[o] + bhh[o];
            float bz = bih[64 + o] + bhh[64 + o];
            float bi_n = bih[128 + o];
            float bh_n = bhh[128 + o];
#pragma unroll
            for (int q = 0; q < 4; ++q) {
                int m = wt * 16 + g * 4 + q;
                if (m < N_NODES) {
                    float r = sigm(acc[fr][q] + br);
                    float z = sigm(acc[2 + fr][q] + bz);
                    float inn = aIN[fr][q] + bi_n;
                    float hn = aHN[fr][q] + bh_n;
                    float nn = tanh_f(inn + r * hn);
                    size_t hix = (size_t)m * 128 + 64 + o;
                    float hp = b2f(catXhi[hix]) + b2f(catXlo[hix]);
                    float hv = (1.f - z) * nn + z * hp;
                    split_store(catYhi, catYlo, hix, hv);
                }
            }
        }
    }
}

// ---------------------------------------------------------------------------
// mlp1: hidden = relu([hinit, h] @ W1 + b1)
__global__ __launch_bounds__(256) void mlp1_gemm(
    const ushort_t* __restrict__ hin_hi, const ushort_t* __restrict__ hin_lo,
    const ushort_t* __restrict__ cathi, const ushort_t* __restrict__ catlo,
    const ushort_t* __restrict__ Bh, const ushort_t* __restrict__ Bl,
    const float* __restrict__ b1,
    ushort_t* __restrict__ hid_hi, ushort_t* __restrict__ hid_lo)
{
    __shared__ ushort_t lds[16384];
    ushort_t* LBh = lds;
    ushort_t* LBl = lds + 8192;
    const int tid = threadIdx.x, lane = tid & 63, wid = tid >> 6;
    const int lr = lane & 15, g = lane >> 4;
    stage_tile<16>(Bh, LBh, 64, tid);
    stage_tile<16>(Bl, LBl, 64, tid);
    __syncthreads();
    for (int wt = blockIdx.x * 4 + wid; wt < NTILES16; wt += gridDim.x * 4) {
        const ushort_t* pAh0 = hin_hi + (size_t)wt * 16 * 64;
        const ushort_t* pAl0 = hin_lo + (size_t)wt * 16 * 64;
        const ushort_t* pAh1 = cathi + (size_t)wt * 16 * 128;
        const ushort_t* pAl1 = catlo + (size_t)wt * 16 * 128;
        f32x4 acc[4];
        f32x4 zz = {0.f, 0.f, 0.f, 0.f};
#pragma unroll
        for (int f = 0; f < 4; ++f) acc[f] = zz;
#pragma unroll
        for (int ks = 0; ks < 4; ++ks) {
            int kg = ks * 4 + g;
            short8 ah, al;
            if (ks < 2) {
                ah = afrag(pAh0, 64, lr, kg);
                al = afrag(pAl0, 64, lr, kg);
            } else {
                ah = afrag(pAh1, 128, lr, (ks - 2) * 4 + g);
                al = afrag(pAl1, 128, lr, (ks - 2) * 4 + g);
            }
#pragma unroll
            for (int f = 0; f < 4; ++f) {
                short8 bh = rdfrag<16>(LBh, f * 16 + lr, kg);
                short8 bl = rdfrag<16>(LBl, f * 16 + lr, kg);
                acc[f] = MFMA(ah, bh, acc[f]);
                acc[f] = MFMA(ah, bl, acc[f]);
                acc[f] = MFMA(al, bh, acc[f]);
            }
        }
#pragma unroll
        for (int f = 0; f < 4; ++f) {
            int o = lr + f * 16;
            float b = b1[o];
#pragma unroll
            for (int q = 0; q < 4; ++q) {
                int m = wt * 16 + g * 4 + q;
                if (m < N_NODES) {
                    float v = fmaxf(acc[f][q] + b, 0.f);
                    split_store(hid_hi, hid_lo, (size_t)m * 64 + o, v);
                }
            }
        }
    }
}

// mlp2: out = tanh(hidden @ W2 + b2)
__global__ __launch_bounds__(256) void mlp2_gemm(
    const ushort_t* __restrict__ hid_hi, const ushort_t* __restrict__ hid_lo,
    const ushort_t* __restrict__ Bh, const ushort_t* __restrict__ Bl,
    const float* __restrict__ b2, float* __restrict__ out)
{
    __shared__ ushort_t lds[8192];
    ushort_t* LBh = lds;
    ushort_t* LBl = lds + 4096;
    const int tid = threadIdx.x, lane = tid & 63, wid = tid >> 6;
    const int lr = lane & 15, g = lane >> 4;
    stage_tile<8>(Bh, LBh, 64, tid);
    stage_tile<8>(Bl, LBl, 64, tid);
    __syncthreads();
    for (int wt = blockIdx.x * 4 + wid; wt < NTILES16; wt += gridDim.x * 4) {
        const ushort_t* pAh = hid_hi + (size_t)wt * 16 * 64;
        const ushort_t* pAl = hid_lo + (size_t)wt * 16 * 64;
        f32x4 acc[4];
        f32x4 zz = {0.f, 0.f, 0.f, 0.f};
#pragma unroll
        for (int f = 0; f < 4; ++f) acc[f] = zz;
#pragma unroll
        for (int ks = 0; ks < 2; ++ks) {
            int kg = ks * 4 + g;
            short8 ah = afrag(pAh, 64, lr, kg);
            short8 al = afrag(pAl, 64, lr, kg);
#pragma unroll
            for (int f = 0; f < 4; ++f) {
                short8 bh = rdfrag<8>(LBh, f * 16 + lr, kg);
                short8 bl = rdfrag<8>(LBl, f * 16 + lr, kg);
                acc[f] = MFMA(ah, bh, acc[f]);
                acc[f] = MFMA(ah, bl, acc[f]);
                acc[f] = MFMA(al, bh, acc[f]);
            }
        }
#pragma unroll
        for (int f = 0; f < 4; ++f) {
            int o = lr + f * 16;
            float b = b2[o];
#pragma unroll
            for (int q = 0; q < 4; ++q) {
                int m = wt * 16 + g * 4 + q;
                if (m < N_NODES)
                    out[(size_t)m * 64 + o] = tanh_f(acc[f][q] + b);
            }
        }
    }
}

// ---------------------------------------------------------------------------
extern "C" void kernel_launch(void* const* d_in, const int* in_sizes, int n_in,
                              void* d_out, int out_size, void* d_ws, size_t ws_size,
                              hipStream_t stream)
{
    const float* x      = (const float*)d_in[0];
    const int*   etype  = (const int*)  d_in[1];
    const int*   src    = (const int*)  d_in[2];
    const int*   dst    = (const int*)  d_in[3];
    const float* W_in   = (const float*)d_in[4];
    const float* b_in   = (const float*)d_in[5];
    const float* edge_W = (const float*)d_in[6];
    const float* edge_b = (const float*)d_in[7];
    const float* gWih   = (const float*)d_in[8];
    const float* gWhh   = (const float*)d_in[9];
    const float* gbih   = (const float*)d_in[10];
    const float* gbhh   = (const float*)d_in[11];
    const float* W1     = (const float*)d_in[12];
    const float* b1     = (const float*)d_in[13];
    const float* W2     = (const float*)d_in[14];
    const float* b2     = (const float*)d_in[15];
    float* out = (float*)d_out;

    char* ws = (char*)d_ws;
    // --- workspace layout (bytes) ---
    // ntr: M2*256 bf16 + 128B pad row = 25,624,704
    ushort_t* ntr     = (ushort_t*)(ws);
    ushort_t* x_hi    = (ushort_t*)(ws);              // alias (init only)
    ushort_t* x_lo    = (ushort_t*)(ws + 9609216);
    ushort_t* hid_hi  = (ushort_t*)(ws);              // alias (post-agg)
    ushort_t* hid_lo  = (ushort_t*)(ws + 6406144);
    ushort_t* catA_hi = (ushort_t*)(ws + 25625088);   // each 12,812,288
    ushort_t* catA_lo = (ushort_t*)(ws + 38437376);
    ushort_t* catB_hi = (ushort_t*)(ws + 51249664);
    ushort_t* catB_lo = (ushort_t*)(ws + 64061952);
    ushort_t* hin_hi  = (ushort_t*)(ws + 76874240);   // each 6,406,144
    ushort_t* hin_lo  = (ushort_t*)(ws + 83280384);
    char* wbase = ws + 89686528;
    ushort_t* BtWin_hi = (ushort_t*)(wbase);          // 6144 elems
    ushort_t* BtWin_lo = (ushort_t*)(wbase + 12288);
    ushort_t* BtE_hi   = (ushort_t*)(wbase + 24576);  // 16384 elems
    ushort_t* Btg_hi   = (ushort_t*)(wbase + 57344);  // 24576 elems
    ushort_t* Btg_lo   = (ushort_t*)(wbase + 106496);
    ushort_t* BtW1_hi  = (ushort_t*)(wbase + 155648); // 8192 elems
    ushort_t* BtW1_lo  = (ushort_t*)(wbase + 172032);
    ushort_t* BtW2_hi  = (ushort_t*)(wbase + 188416); // 4096 elems
    ushort_t* BtW2_lo  = (ushort_t*)(wbase + 196608);
    char* cbase = ws + 89891328;
    int* deg    = (int*)(cbase);
    int* rowp   = (int*)(cbase + 200192);
    int* cursor = (int*)(cbase + 400640);
    int* ss     = (int*)(cbase + 600832);
    int* bsum   = (int*)(cbase + 3800832);
    int* boff   = (int*)(cbase + 3801856);

    const int edge_tblocks = (N_EDGES + 255) / 256;   // 3125
    const int agg_blocks = (N_NODES + 3) / 4;         // 12500
    const int GB = 782;   // GEMM grid: 782*4 waves = 3128 = NTILES16

    // zero deg + ntr pad row
    hipMemsetAsync(deg, 0, N_NODES * sizeof(int), stream);
    hipMemsetAsync(ws + (size_t)M2 * 512, 0, 128, stream);

    // CSR build (two-level scan)
    deg_kernel<<<edge_tblocks, 256, 0, stream>>>(dst, deg);
    scan_p1<<<SCAN_NB, 256, 0, stream>>>(deg, bsum);
    scan_p2<<<1, 256, 0, stream>>>(bsum, boff, rowp);
    scan_p3<<<SCAN_NB, 256, 0, stream>>>(deg, boff, rowp, cursor);
    fill_kernel<<<edge_tblocks, 256, 0, stream>>>(src, etype, dst, cursor, ss);

    // weight prep + x split
    prep_w_kernel<<<(59392 + 255) / 256, 256, 0, stream>>>(
        W_in, edge_W, gWih, gWhh, W1, W2,
        BtWin_hi, BtWin_lo, BtE_hi, Btg_hi, Btg_lo,
        BtW1_hi, BtW1_lo, BtW2_hi, BtW2_lo);
    split_x_kernel<<<(M2 * 96 + 255) / 256, 256, 0, stream>>>(x, x_hi, x_lo);

    // init -> catA.h + hinit
    init_gemm<<<GB, 256, 0, stream>>>(x_hi, x_lo, BtWin_hi, BtWin_lo, b_in,
                                      catA_hi, catA_lo, hin_hi, hin_lo);

    ushort_t *Xhi = catA_hi, *Xlo = catA_lo, *Yhi = catB_hi, *Ylo = catB_lo;
    for (int s = 0; s < STEPS; ++s) {
        nt_gemm<<<GB, 256, 0, stream>>>(Xhi + 64, BtE_hi, edge_b, ntr);
        agg_kernel<<<agg_blocks, 256, 0, stream>>>(ntr, rowp, ss, Xhi, Xlo);
        gru_gemm<<<GB, 256, 0, stream>>>(Xhi, Xlo, Btg_hi, Btg_lo, gbih, gbhh,
                                         Yhi, Ylo, 0);
        gru_gemm<<<GB, 256, 0, stream>>>(Xhi, Xlo, Btg_hi + 12288, Btg_lo + 12288,
                                         gbih, gbhh, Yhi, Ylo, 32);
        ushort_t* t;
        t = Xhi; Xhi = Yhi; Yhi = t;
        t = Xlo; Xlo = Ylo; Ylo = t;
    }
    // after 4 steps final h is in catA (Xhi == catA_hi)

    mlp1_gemm<<<GB, 256, 0, stream>>>(hin_hi, hin_lo, Xhi + 64, Xlo + 64,
                                      BtW1_hi, BtW1_lo, b1, hid_hi, hid_lo);
    mlp2_gemm<<<GB, 256, 0, stream>>>(hid_hi, hid_lo, BtW2_hi, BtW2_lo, b2, out);
}

// Round 6
// 517.371 us; speedup vs baseline: 3.6949x; 1.0377x over previous
//
#include <hip/hip_runtime.h>
#include <hip/hip_bf16.h>

#define N_NODES 50000
#define M2      50048          // padded to multiple of 64
#define N_EDGES 800000
#define H 64
#define F 74
#define T 4
#define STEPS 4
#define NTILES16 (M2/16)       // 3128 wave-tiles of 16 rows
#define NTILES32 (M2/32)       // 1564 wave-tiles of 32 rows
#define PAD_REC  (M2*4)        // zeroed pad row in ntr
#define SCAN_NB  196           // ceil(N_NODES/256)

using short8 = __attribute__((ext_vector_type(8))) short;
using f32x4  = __attribute__((ext_vector_type(4))) float;
typedef unsigned short ushort_t;

#define MFMA(a,b,c) __builtin_amdgcn_mfma_f32_16x16x32_bf16(a,b,c,0,0,0)

static __device__ inline float b2f(ushort_t u) {
    union { unsigned int i; float f; } c; c.i = ((unsigned int)u) << 16; return c.f;
}
static __device__ inline ushort_t f2b(float v) {
    union { __hip_bfloat16 b; ushort_t u; } c; c.b = __float2bfloat16(v); return c.u;
}
static __device__ inline void split_store(ushort_t* hi, ushort_t* lo, size_t ix, float v) {
    ushort_t h = f2b(v);
    hi[ix] = h;
    lo[ix] = f2b(v - b2f(h));
}
static __device__ inline float sigm(float x) { return 1.f / (1.f + __expf(-x)); }
static __device__ inline float tanh_f(float x) {
    float e2 = __expf(2.f * x); return 1.f - 2.f / (e2 + 1.f);
}

// ---- LDS staging of B-tiles (bf16, row-major [rows][KW8*8]) with XOR swizzle
template<int KW8>
static __device__ inline void stage_tile(const ushort_t* __restrict__ g, ushort_t* l,
                                         int rows, int tid) {
    const int chunks = rows * KW8;
    for (int i = tid; i < chunks; i += 256) {
        int row = i / KW8, kg = i - row * KW8;
        short8 v = *(const short8*)(g + (size_t)row * (KW8 * 8) + kg * 8);
        int b = (row * (KW8 * 16) + kg * 16) ^ ((row & 7) << 4);
        *(short8*)((char*)l + b) = v;
    }
}
template<int KW8>
static __device__ inline short8 rdfrag(const ushort_t* l, int row, int kg) {
    int b = (row * (KW8 * 16) + kg * 16) ^ ((row & 7) << 4);
    return *(const short8*)((const char*)l + b);
}
static __device__ inline short8 afrag(const ushort_t* base, int LD, int row, int kg) {
    return *(const short8*)(base + (size_t)row * LD + kg * 8);
}

// ---------------------------------------------------------------------------
// split x into hi/lo bf16 [M2][96]
__global__ __launch_bounds__(256) void split_x_kernel(
    const float* __restrict__ x, ushort_t* __restrict__ hi, ushort_t* __restrict__ lo)
{
    int idx = blockIdx.x * 256 + threadIdx.x;
    int total = M2 * 96;
    if (idx >= total) return;
    int row = idx / 96, c = idx - row * 96;
    float v = (row < N_NODES && c < F) ? x[(size_t)row * F + c] : 0.f;
    split_store(hi, lo, idx, v);
}

// ---------------------------------------------------------------------------
// fused weight prep: all B^T transforms in one dispatch.
// ranges: [0,6144) Win | [6144,22528) E(hi only) | [22528,47104) gru |
//         [47104,55296) W1 | [55296,59392) W2
__global__ __launch_bounds__(256) void prep_w_kernel(
    const float* __restrict__ W_in, const float* __restrict__ eW,
    const float* __restrict__ Wih, const float* __restrict__ Whh,
    const float* __restrict__ W1, const float* __restrict__ W2,
    ushort_t* __restrict__ BtWin_hi, ushort_t* __restrict__ BtWin_lo,
    ushort_t* __restrict__ BtE_hi,
    ushort_t* __restrict__ Btg_hi, ushort_t* __restrict__ Btg_lo,
    ushort_t* __restrict__ BtW1_hi, ushort_t* __restrict__ BtW1_lo,
    ushort_t* __restrict__ BtW2_hi, ushort_t* __restrict__ BtW2_lo)
{
    int idx = blockIdx.x * 256 + threadIdx.x;
    if (idx < 6144) {                       // Win: [64 col][96 k]
        int col = idx / 96, k = idx - col * 96;
        float v = (k < F) ? W_in[(size_t)k * 64 + col] : 0.f;
        split_store(BtWin_hi, BtWin_lo, idx, v);
    } else if (idx < 22528) {               // E: [256 c][64 k], hi only
        int i = idx - 6144;
        int c = i >> 6, k = i & 63;
        float v = eW[(c >> 6) * 4096 + k * 64 + (c & 63)];
        BtE_hi[i] = f2b(v);
    } else if (idx < 47104) {               // gru: [192 row=gatecol][128 k]
        int i = idx - 22528;
        int row = i >> 7, k = i & 127;
        float v = (k < 64) ? Wih[(size_t)k * 192 + row]
                           : Whh[(size_t)(k - 64) * 192 + row];
        split_store(Btg_hi, Btg_lo, i, v);
    } else if (idx < 55296) {               // W1: [64 col][128 k]
        int i = idx - 47104;
        int col = i >> 7, k = i & 127;
        float v = W1[(size_t)k * 64 + col];
        split_store(BtW1_hi, BtW1_lo, i, v);
    } else if (idx < 59392) {               // W2: [64 col][64 k]
        int i = idx - 55296;
        int col = i >> 6, k = i & 63;
        float v = W2[(size_t)k * 64 + col];
        split_store(BtW2_hi, BtW2_lo, i, v);
    }
}

// ---------------------------------------------------------------------------
// CSR build
__global__ __launch_bounds__(256) void deg_kernel(
    const int* __restrict__ dst, int* __restrict__ deg)
{
    int e = blockIdx.x * 256 + threadIdx.x;
    if (e < N_EDGES) atomicAdd(&deg[dst[e]], 1);
}

__global__ __launch_bounds__(256) void scan_p1(
    const int* __restrict__ deg, int* __restrict__ bsum)
{
    __shared__ int ws4[4];
    const int tid = threadIdx.x, lane = tid & 63, w = tid >> 6;
    int idx = blockIdx.x * 256 + tid;
    int v = (idx < N_NODES) ? deg[idx] : 0;
#pragma unroll
    for (int off = 32; off >= 1; off >>= 1) v += __shfl_down(v, off, 64);
    if (lane == 0) ws4[w] = v;
    __syncthreads();
    if (tid == 0) bsum[blockIdx.x] = ws4[0] + ws4[1] + ws4[2] + ws4[3];
}

__global__ __launch_bounds__(256) void scan_p2(
    const int* __restrict__ bsum, int* __restrict__ boff, int* __restrict__ rowp)
{
    __shared__ int ws4[4];
    const int tid = threadIdx.x, lane = tid & 63, w = tid >> 6;
    int v = (tid < SCAN_NB) ? bsum[tid] : 0;
    int x = v;
#pragma unroll
    for (int off = 1; off < 64; off <<= 1) {
        int u = __shfl_up(x, off, 64);
        if (lane >= off) x += u;
    }
    if (lane == 63) ws4[w] = x;
    __syncthreads();
    int a0 = ws4[0], a1 = ws4[1], a2 = ws4[2];
    int add = (w > 0 ? a0 : 0) + (w > 1 ? a1 : 0) + (w > 2 ? a2 : 0);
    if (tid < SCAN_NB) boff[tid] = add + x - v;
    if (tid == 255) rowp[N_NODES] = add + x;
}

__global__ __launch_bounds__(256) void scan_p3(
    const int* __restrict__ deg, const int* __restrict__ boff,
    int* __restrict__ rowp, int* __restrict__ cursor)
{
    __shared__ int ws4[4];
    const int tid = threadIdx.x, lane = tid & 63, w = tid >> 6;
    int idx = blockIdx.x * 256 + tid;
    int v = (idx < N_NODES) ? deg[idx] : 0;
    int x = v;
#pragma unroll
    for (int off = 1; off < 64; off <<= 1) {
        int u = __shfl_up(x, off, 64);
        if (lane >= off) x += u;
    }
    if (lane == 63) ws4[w] = x;
    __syncthreads();
    int a0 = ws4[0], a1 = ws4[1], a2 = ws4[2];
    int add = boff[blockIdx.x]
            + (w > 0 ? a0 : 0) + (w > 1 ? a1 : 0) + (w > 2 ? a2 : 0);
    int excl = add + x - v;
    if (idx < N_NODES) { rowp[idx] = excl; cursor[idx] = excl; }
}

__global__ __launch_bounds__(256) void fill_kernel(
    const int* __restrict__ src, const int* __restrict__ etype,
    const int* __restrict__ dst, int* __restrict__ cursor, int* __restrict__ ss)
{
    int e = blockIdx.x * 256 + threadIdx.x;
    if (e < N_EDGES) {
        int p = atomicAdd(&cursor[dst[e]], 1);
        ss[p] = src[e] * 4 + etype[e];
    }
}

// ---------------------------------------------------------------------------
// init: C = x @ W_in + b_in  (full double-bf16, runs once)
__global__ __launch_bounds__(256) void init_gemm(
    const ushort_t* __restrict__ xhi, const ushort_t* __restrict__ xlo,
    const ushort_t* __restrict__ Bh, const ushort_t* __restrict__ Bl,
    const float* __restrict__ b_in,
    ushort_t* __restrict__ cat_hi, ushort_t* __restrict__ cat_lo,
    ushort_t* __restrict__ hin_hi, ushort_t* __restrict__ hin_lo)
{
    __shared__ ushort_t lds[12288];
    ushort_t* LBh = lds;
    ushort_t* LBl = lds + 6144;
    const int tid = threadIdx.x, lane = tid & 63, wid = tid >> 6;
    const int lr = lane & 15, g = lane >> 4;
    stage_tile<12>(Bh, LBh, 64, tid);
    stage_tile<12>(Bl, LBl, 64, tid);
    __syncthreads();
    for (int wt = blockIdx.x * 4 + wid; wt < NTILES16; wt += gridDim.x * 4) {
        const ushort_t* pAh = xhi + (size_t)wt * 16 * 96;
        const ushort_t* pAl = xlo + (size_t)wt * 16 * 96;
        f32x4 acc[4];
        f32x4 zz = {0.f, 0.f, 0.f, 0.f};
#pragma unroll
        for (int f = 0; f < 4; ++f) acc[f] = zz;
#pragma unroll
        for (int ks = 0; ks < 3; ++ks) {
            int kg = ks * 4 + g;
            short8 ah = afrag(pAh, 96, lr, kg);
            short8 al = afrag(pAl, 96, lr, kg);
#pragma unroll
            for (int f = 0; f < 4; ++f) {
                short8 bh = rdfrag<12>(LBh, f * 16 + lr, kg);
                short8 bl = rdfrag<12>(LBl, f * 16 + lr, kg);
                acc[f] = MFMA(ah, bh, acc[f]);
                acc[f] = MFMA(ah, bl, acc[f]);
                acc[f] = MFMA(al, bh, acc[f]);
            }
        }
#pragma unroll
        for (int f = 0; f < 4; ++f) {
            int o = lr + f * 16;
            float b = b_in[o];
#pragma unroll
            for (int q = 0; q < 4; ++q) {
                int m = wt * 16 + g * 4 + q;
                if (m < N_NODES) {
                    float v = acc[f][q] + b;
                    split_store(cat_hi, cat_lo, (size_t)m * 128 + 64 + o, v);
                    split_store(hin_hi, hin_lo, (size_t)m * 64 + o, v);
                }
            }
        }
    }
}

// ---------------------------------------------------------------------------
// nt (single-bf16, 32-row tiles): ntr[m,c] = relu( h @ edge_W + edge_b )
// 32-row A tiles double B-frag reuse (32 ds_read per 64 MFMA).
__global__ __launch_bounds__(256) void nt_gemm(
    const ushort_t* __restrict__ ahi,          // cat hi, pre-offset +64, LD=128
    const ushort_t* __restrict__ Bh,           // BtE_hi [256][64]
    const float* __restrict__ edge_b, ushort_t* __restrict__ ntr)
{
    __shared__ ushort_t lds[16384];            // 32 KB (exact fit)
    const int tid = threadIdx.x, lane = tid & 63, wid = tid >> 6;
    const int lr = lane & 15, g = lane >> 4;
    stage_tile<8>(Bh, lds, 256, tid);
    __syncthreads();
    for (int wt = blockIdx.x * 4 + wid; wt < NTILES32; wt += gridDim.x * 4) {
        const ushort_t* pA = ahi + (size_t)wt * 32 * 128;
        f32x4 acc[2][16];
        f32x4 zz = {0.f, 0.f, 0.f, 0.f};
#pragma unroll
        for (int s = 0; s < 2; ++s)
#pragma unroll
            for (int f = 0; f < 16; ++f) acc[s][f] = zz;
#pragma unroll
        for (int ks = 0; ks < 2; ++ks) {
            int kg = ks * 4 + g;
            short8 a0 = afrag(pA, 128, lr, kg);
            short8 a1 = afrag(pA, 128, 16 + lr, kg);
#pragma unroll
            for (int f = 0; f < 16; ++f) {
                short8 bh = rdfrag<8>(lds, f * 16 + lr, kg);
                acc[0][f] = MFMA(a0, bh, acc[0][f]);
                acc[1][f] = MFMA(a1, bh, acc[1][f]);
            }
        }
#pragma unroll
        for (int s = 0; s < 2; ++s) {
#pragma unroll
            for (int f = 0; f < 16; ++f) {
                int colg = lr + f * 16;
                float b = edge_b[colg >> 6];
#pragma unroll
                for (int q = 0; q < 4; ++q) {
                    int m = wt * 32 + s * 16 + g * 4 + q;
                    if (m < N_NODES) {
                        float v = fmaxf(acc[s][f][q] + b, 0.f);
                        ntr[(size_t)m * 256 + colg] = f2b(v);
                    }
                }
            }
        }
    }
}

// ---------------------------------------------------------------------------
// agg: branchless 16-wide gather batches; pad gathers hit the zeroed pad row.
__global__ __launch_bounds__(256, 4) void agg_kernel(
    const ushort_t* __restrict__ ntr, const int* __restrict__ row_ptr,
    const int* __restrict__ ss, ushort_t* __restrict__ cat_hi,
    ushort_t* __restrict__ cat_lo)
{
    const int lane = threadIdx.x & 63;
    const int w = __builtin_amdgcn_readfirstlane((int)(threadIdx.x >> 6));
    const int d = blockIdx.x * 4 + w;
    if (d >= N_NODES) return;
    const int beg = row_ptr[d];
    const int end = row_ptr[d + 1];
    float acc = 0.f;
    for (int p = beg; p < end; p += 16) {
        float v[16];
#pragma unroll
        for (int i = 0; i < 16; ++i) {
            bool inb = (p + i) < end;
            int rec = ss[inb ? (p + i) : beg];
            rec = inb ? rec : PAD_REC;
            v[i] = b2f(ntr[(size_t)rec * 64 + lane]);
        }
        float s0 = (v[0] + v[1]) + (v[2] + v[3]);
        float s1 = (v[4] + v[5]) + (v[6] + v[7]);
        float s2 = (v[8] + v[9]) + (v[10] + v[11]);
        float s3 = (v[12] + v[13]) + (v[14] + v[15]);
        acc += (s0 + s1) + (s2 + s3);
    }
    split_store(cat_hi, cat_lo, (size_t)d * 128 + lane, acc);
}

// ---------------------------------------------------------------------------
// gru (single fused dispatch, all 64 output cols):
// B hi [192][128] in LDS (48 KB); n-gate B lo read from global (L2-hot).
// r,z gates: 2-term (ah*bh + al*bh); n-gate: 3-term.
__global__ __launch_bounds__(256) void gru_gemm(
    const ushort_t* __restrict__ catXhi, const ushort_t* __restrict__ catXlo,
    const ushort_t* __restrict__ Bh,     // Btg_hi [192][128]
    const ushort_t* __restrict__ Bl,     // Btg_lo [192][128] (rows 128.. used)
    const float* __restrict__ bih, const float* __restrict__ bhh,
    ushort_t* __restrict__ catYhi, ushort_t* __restrict__ catYlo)
{
    __shared__ ushort_t lds[24576];      // 48 KB
    const int tid = threadIdx.x, lane = tid & 63, wid = tid >> 6;
    const int lr = lane & 15, g = lane >> 4;
    stage_tile<16>(Bh, lds, 192, tid);
    __syncthreads();
    for (int wt = blockIdx.x * 4 + wid; wt < NTILES16; wt += gridDim.x * 4) {
        const ushort_t* pAh = catXhi + (size_t)wt * 16 * 128;
        const ushort_t* pAl = catXlo + (size_t)wt * 16 * 128;
        f32x4 aR[4], aZ[4], aIN[4], aHN[4];
        f32x4 zz = {0.f, 0.f, 0.f, 0.f};
#pragma unroll
        for (int f = 0; f < 4; ++f) { aR[f] = zz; aZ[f] = zz; aIN[f] = zz; aHN[f] = zz; }
#pragma unroll
        for (int ks = 0; ks < 4; ++ks) {
            int kg = ks * 4 + g;
            short8 ah = afrag(pAh, 128, lr, kg);
            short8 al = afrag(pAl, 128, lr, kg);
#pragma unroll
            for (int f = 0; f < 4; ++f) {
                short8 bhr = rdfrag<16>(lds, f * 16 + lr, kg);
                aR[f] = MFMA(ah, bhr, aR[f]);
                aR[f] = MFMA(al, bhr, aR[f]);
                short8 bhz = rdfrag<16>(lds, 64 + f * 16 + lr, kg);
                aZ[f] = MFMA(ah, bhz, aZ[f]);
                aZ[f] = MFMA(al, bhz, aZ[f]);
                short8 bhn = rdfrag<16>(lds, 128 + f * 16 + lr, kg);
                short8 bln = afrag(Bl, 128, 128 + f * 16 + lr, kg);
                if (ks < 2) {
                    aIN[f] = MFMA(ah, bhn, aIN[f]);
                    aIN[f] = MFMA(al, bhn, aIN[f]);
                    aIN[f] = MFMA(ah, bln, aIN[f]);
                } else {
                    aHN[f] = MFMA(ah, bhn, aHN[f]);
                    aHN[f] = MFMA(al, bhn, aHN[f]);
                    aHN[f] = MFMA(ah, bln, aHN[f]);
                }
            }
        }
#pragma unroll
        for (int f = 0; f < 4; ++f) {
            int o = f * 16 + lr;
            float br = bih[o] + bhh[o];
            float bz = bih[64 + o] + bhh[64 + o];
            float bi_n = bih[128 + o];
            float bh_n = bhh[128 + o];
#pragma unroll
            for (int q = 0; q < 4; ++q) {
                int m = wt * 16 + g * 4 + q;
                if (m < N_NODES) {
                    float r = sigm(aR[f][q] + br);
                    float z = sigm(aZ[f][q] + bz);
                    float inn = aIN[f][q] + bi_n;
                    float hn = aHN[f][q] + bh_n;
                    float nn = tanh_f(inn + r * hn);
                    size_t hix = (size_t)m * 128 + 64 + o;
                    float hp = b2f(catXhi[hix]) + b2f(catXlo[hix]);
                    float hv = (1.f - z) * nn + z * hp;
                    split_store(catYhi, catYlo, hix, hv);
                }
            }
        }
    }
}

// ---------------------------------------------------------------------------
// mlp1: hidden = relu([hinit, h] @ W1 + b1)
__global__ __launch_bounds__(256) void mlp1_gemm(
    const ushort_t* __restrict__ hin_hi, const ushort_t* __restrict__ hin_lo,
    const ushort_t* __restrict__ cathi, const ushort_t* __restrict__ catlo,
    const ushort_t* __restrict__ Bh, const ushort_t* __restrict__ Bl,
    const float* __restrict__ b1,
    ushort_t* __restrict__ hid_hi, ushort_t* __restrict__ hid_lo)
{
    __shared__ ushort_t lds[16384];
    ushort_t* LBh = lds;
    ushort_t* LBl = lds + 8192;
    const int tid = threadIdx.x, lane = tid & 63, wid = tid >> 6;
    const int lr = lane & 15, g = lane >> 4;
    stage_tile<16>(Bh, LBh, 64, tid);
    stage_tile<16>(Bl, LBl, 64, tid);
    __syncthreads();
    for (int wt = blockIdx.x * 4 + wid; wt < NTILES16; wt += gridDim.x * 4) {
        const ushort_t* pAh0 = hin_hi + (size_t)wt * 16 * 64;
        const ushort_t* pAl0 = hin_lo + (size_t)wt * 16 * 64;
        const ushort_t* pAh1 = cathi + (size_t)wt * 16 * 128;
        const ushort_t* pAl1 = catlo + (size_t)wt * 16 * 128;
        f32x4 acc[4];
        f32x4 zz = {0.f, 0.f, 0.f, 0.f};
#pragma unroll
        for (int f = 0; f < 4; ++f) acc[f] = zz;
#pragma unroll
        for (int ks = 0; ks < 4; ++ks) {
            int kg = ks * 4 + g;
            short8 ah, al;
            if (ks < 2) {
                ah = afrag(pAh0, 64, lr, kg);
                al = afrag(pAl0, 64, lr, kg);
            } else {
                ah = afrag(pAh1, 128, lr, (ks - 2) * 4 + g);
                al = afrag(pAl1, 128, lr, (ks - 2) * 4 + g);
            }
#pragma unroll
            for (int f = 0; f < 4; ++f) {
                short8 bh = rdfrag<16>(LBh, f * 16 + lr, kg);
                short8 bl = rdfrag<16>(LBl, f * 16 + lr, kg);
                acc[f] = MFMA(ah, bh, acc[f]);
                acc[f] = MFMA(ah, bl, acc[f]);
                acc[f] = MFMA(al, bh, acc[f]);
            }
        }
#pragma unroll
        for (int f = 0; f < 4; ++f) {
            int o = lr + f * 16;
            float b = b1[o];
#pragma unroll
            for (int q = 0; q < 4; ++q) {
                int m = wt * 16 + g * 4 + q;
                if (m < N_NODES) {
                    float v = fmaxf(acc[f][q] + b, 0.f);
                    split_store(hid_hi, hid_lo, (size_t)m * 64 + o, v);
                }
            }
        }
    }
}

// mlp2: out = tanh(hidden @ W2 + b2)
__global__ __launch_bounds__(256) void mlp2_gemm(
    const ushort_t* __restrict__ hid_hi, const ushort_t* __restrict__ hid_lo,
    const ushort_t* __restrict__ Bh, const ushort_t* __restrict__ Bl,
    const float* __restrict__ b2, float* __restrict__ out)
{
    __shared__ ushort_t lds[8192];
    ushort_t* LBh = lds;
    ushort_t* LBl = lds + 4096;
    const int tid = threadIdx.x, lane = tid & 63, wid = tid >> 6;
    const int lr = lane & 15, g = lane >> 4;
    stage_tile<8>(Bh, LBh, 64, tid);
    stage_tile<8>(Bl, LBl, 64, tid);
    __syncthreads();
    for (int wt = blockIdx.x * 4 + wid; wt < NTILES16; wt += gridDim.x * 4) {
        const ushort_t* pAh = hid_hi + (size_t)wt * 16 * 64;
        const ushort_t* pAl = hid_lo + (size_t)wt * 16 * 64;
        f32x4 acc[4];
        f32x4 zz = {0.f, 0.f, 0.f, 0.f};
#pragma unroll
        for (int f = 0; f < 4; ++f) acc[f] = zz;
#pragma unroll
        for (int ks = 0; ks < 2; ++ks) {
            int kg = ks * 4 + g;
            short8 ah = afrag(pAh, 64, lr, kg);
            short8 al = afrag(pAl, 64, lr, kg);
#pragma unroll
            for (int f = 0; f < 4; ++f) {
                short8 bh = rdfrag<8>(LBh, f * 16 + lr, kg);
                short8 bl = rdfrag<8>(LBl, f * 16 + lr, kg);
                acc[f] = MFMA(ah, bh, acc[f]);
                acc[f] = MFMA(ah, bl, acc[f]);
                acc[f] = MFMA(al, bh, acc[f]);
            }
        }
#pragma unroll
        for (int f = 0; f < 4; ++f) {
            int o = lr + f * 16;
            float b = b2[o];
#pragma unroll
            for (int q = 0; q < 4; ++q) {
                int m = wt * 16 + g * 4 + q;
                if (m < N_NODES)
                    out[(size_t)m * 64 + o] = tanh_f(acc[f][q] + b);
            }
        }
    }
}

// ---------------------------------------------------------------------------
extern "C" void kernel_launch(void* const* d_in, const int* in_sizes, int n_in,
                              void* d_out, int out_size, void* d_ws, size_t ws_size,
                              hipStream_t stream)
{
    const float* x      = (const float*)d_in[0];
    const int*   etype  = (const int*)  d_in[1];
    const int*   src    = (const int*)  d_in[2];
    const int*   dst    = (const int*)  d_in[3];
    const float* W_in   = (const float*)d_in[4];
    const float* b_in   = (const float*)d_in[5];
    const float* edge_W = (const float*)d_in[6];
    const float* edge_b = (const float*)d_in[7];
    const float* gWih   = (const float*)d_in[8];
    const float* gWhh   = (const float*)d_in[9];
    const float* gbih   = (const float*)d_in[10];
    const float* gbhh   = (const float*)d_in[11];
    const float* W1     = (const float*)d_in[12];
    const float* b1     = (const float*)d_in[13];
    const float* W2     = (const float*)d_in[14];
    const float* b2     = (const float*)d_in[15];
    float* out = (float*)d_out;

    char* ws = (char*)d_ws;
    // --- workspace layout (bytes) ---
    ushort_t* ntr     = (ushort_t*)(ws);              // M2*256 bf16 + pad row
    ushort_t* x_hi    = (ushort_t*)(ws);              // alias (init only)
    ushort_t* x_lo    = (ushort_t*)(ws + 9609216);
    ushort_t* hid_hi  = (ushort_t*)(ws);              // alias (post-agg)
    ushort_t* hid_lo  = (ushort_t*)(ws + 6406144);
    ushort_t* catA_hi = (ushort_t*)(ws + 25625088);   // each 12,812,288
    ushort_t* catA_lo = (ushort_t*)(ws + 38437376);
    ushort_t* catB_hi = (ushort_t*)(ws + 51249664);
    ushort_t* catB_lo = (ushort_t*)(ws + 64061952);
    ushort_t* hin_hi  = (ushort_t*)(ws + 76874240);   // each 6,406,144
    ushort_t* hin_lo  = (ushort_t*)(ws + 83280384);
    char* wbase = ws + 89686528;
    ushort_t* BtWin_hi = (ushort_t*)(wbase);          // 6144 elems
    ushort_t* BtWin_lo = (ushort_t*)(wbase + 12288);
    ushort_t* BtE_hi   = (ushort_t*)(wbase + 24576);  // 16384 elems
    ushort_t* Btg_hi   = (ushort_t*)(wbase + 57344);  // 24576 elems [192][128]
    ushort_t* Btg_lo   = (ushort_t*)(wbase + 106496);
    ushort_t* BtW1_hi  = (ushort_t*)(wbase + 155648); // 8192 elems
    ushort_t* BtW1_lo  = (ushort_t*)(wbase + 172032);
    ushort_t* BtW2_hi  = (ushort_t*)(wbase + 188416); // 4096 elems
    ushort_t* BtW2_lo  = (ushort_t*)(wbase + 196608);
    char* cbase = ws + 89891328;
    int* deg    = (int*)(cbase);
    int* rowp   = (int*)(cbase + 200192);
    int* cursor = (int*)(cbase + 400640);
    int* ss     = (int*)(cbase + 600832);
    int* bsum   = (int*)(cbase + 3800832);
    int* boff   = (int*)(cbase + 3801856);

    const int edge_tblocks = (N_EDGES + 255) / 256;   // 3125
    const int agg_blocks = (N_NODES + 3) / 4;         // 12500
    const int GB = 782;    // 16-row GEMM grid: 782*4 = 3128 = NTILES16
    const int GB32 = 391;  // 32-row GEMM grid: 391*4 = 1564 = NTILES32

    // zero deg + ntr pad row
    hipMemsetAsync(deg, 0, N_NODES * sizeof(int), stream);
    hipMemsetAsync(ws + (size_t)M2 * 512, 0, 128, stream);

    // CSR build (two-level scan)
    deg_kernel<<<edge_tblocks, 256, 0, stream>>>(dst, deg);
    scan_p1<<<SCAN_NB, 256, 0, stream>>>(deg, bsum);
    scan_p2<<<1, 256, 0, stream>>>(bsum, boff, rowp);
    scan_p3<<<SCAN_NB, 256, 0, stream>>>(deg, boff, rowp, cursor);
    fill_kernel<<<edge_tblocks, 256, 0, stream>>>(src, etype, dst, cursor, ss);

    // weight prep + x split
    prep_w_kernel<<<(59392 + 255) / 256, 256, 0, stream>>>(
        W_in, edge_W, gWih, gWhh, W1, W2,
        BtWin_hi, BtWin_lo, BtE_hi, Btg_hi, Btg_lo,
        BtW1_hi, BtW1_lo, BtW2_hi, BtW2_lo);
    split_x_kernel<<<(M2 * 96 + 255) / 256, 256, 0, stream>>>(x, x_hi, x_lo);

    // init -> catA.h + hinit
    init_gemm<<<GB, 256, 0, stream>>>(x_hi, x_lo, BtWin_hi, BtWin_lo, b_in,
                                      catA_hi, catA_lo, hin_hi, hin_lo);

    ushort_t *Xhi = catA_hi, *Xlo = catA_lo, *Yhi = catB_hi, *Ylo = catB_lo;
    for (int s = 0; s < STEPS; ++s) {
        nt_gemm<<<GB32, 256, 0, stream>>>(Xhi + 64, BtE_hi, edge_b, ntr);
        agg_kernel<<<agg_blocks, 256, 0, stream>>>(ntr, rowp, ss, Xhi, Xlo);
        gru_gemm<<<GB, 256, 0, stream>>>(Xhi, Xlo, Btg_hi, Btg_lo, gbih, gbhh,
                                         Yhi, Ylo);
        ushort_t* t;
        t = Xhi; Xhi = Yhi; Yhi = t;
        t = Xlo; Xlo = Ylo; Ylo = t;
    }
    // after 4 steps final h is in catA (Xhi == catA_hi)

    mlp1_gemm<<<GB, 256, 0, stream>>>(hin_hi, hin_lo, Xhi + 64, Xlo + 64,
                                      BtW1_hi, BtW1_lo, b1, hid_hi, hid_lo);
    mlp2_gemm<<<GB, 256, 0, stream>>>(hid_hi, hid_lo, BtW2_hi, BtW2_lo, b2, out);
}